// Round 12
// baseline (358.327 us; speedup 1.0000x reference)
//
#include <hip/hip_runtime.h>
#include <hip/hip_bf16.h>

#define N_NODES 50000
#define N_EDGES 1600000
#define N_GRAPHS 64
#define D_IN 128
#define D_H 512
#define D_OUT 16

// atomic-free CSR build: buckets of 256 rows
#define NBUK 196                      // ceil(50000/256)
#define BUK_CAP 9216                  // per-bucket capacity: mean 8192 + ~11 sigma
#define P1_EDGES 8192                 // edges per partition block
#define P1_BLOCKS ((N_EDGES + P1_EDGES - 1) / P1_EDGES)   // 196

#define HALF_U 32                     // 32 u32 = 64 bf16 features = 128 B per half-row

typedef short bf16x8 __attribute__((ext_vector_type(8)));
typedef float f32x4 __attribute__((ext_vector_type(4)));

static __device__ __forceinline__ unsigned short f2bf(float f) {
    __hip_bfloat16 h = __float2bfloat16(f);   // RNE
    return *(unsigned short*)&h;
}

// ---------------------------------------------------------------- CSR build (atomic-free)
// P1 with per-wave sub-histograms: 4x less LDS-atomic contention than single hist.

__global__ __launch_bounds__(256) void partition_edges(const int* __restrict__ row,
                                                       const int* __restrict__ col,
                                                       int* __restrict__ bucket_cnt,
                                                       unsigned* __restrict__ edge_buf) {
    __shared__ unsigned recs[P1_EDGES];     // 32 KB
    __shared__ unsigned sorted[P1_EDGES];   // 32 KB
    __shared__ int hist4[4][NBUK];          // per-wave counts -> per-wave local bases
    __shared__ int cur4[4][NBUK];
    __shared__ int gbase[NBUK];
    __shared__ int scan[256];
    int tid = threadIdx.x;
    int wave = tid >> 6;
    int e0 = blockIdx.x * P1_EDGES;
    int m = N_EDGES - e0; if (m > P1_EDGES) m = P1_EDGES;

    for (int i = tid; i < 4 * NBUK; i += 256) {
        hist4[0][i] = 0;            // flat-zero both arrays (hist4 then cur4 contiguous? not
    }                               // guaranteed -> zero separately below)
    for (int i = tid; i < 4 * NBUK; i += 256) ((int*)cur4)[i] = 0;
    __syncthreads();
    for (int i = tid; i < m; i += 256) {
        int r = row[e0 + i];
        int c = col[e0 + i];
        int buk = r >> 8;
        recs[i] = ((unsigned)buk << 24) | ((unsigned)(r & 255) << 16) | (unsigned)c;
        atomicAdd(&hist4[wave][buk], 1);
    }
    __syncthreads();
    int tot = 0;
    if (tid < NBUK) tot = hist4[0][tid] + hist4[1][tid] + hist4[2][tid] + hist4[3][tid];
    scan[tid] = (tid < NBUK) ? tot : 0;
    __syncthreads();
    for (int off = 1; off < 256; off <<= 1) {
        int v = (tid >= off) ? scan[tid - off] : 0;
        __syncthreads();
        scan[tid] += v;
        __syncthreads();
    }
    if (tid < NBUK) {
        int run = (tid == 0) ? 0 : scan[tid - 1];   // block-local excl base
        gbase[tid] = (tot > 0) ? atomicAdd(&bucket_cnt[tid], tot) : 0;  // reserve range
#pragma unroll
        for (int w = 0; w < 4; ++w) {               // per-wave local bases
            int c = hist4[w][tid];
            hist4[w][tid] = run;
            run += c;
        }
    }
    __syncthreads();
    for (int i = tid; i < m; i += 256) {            // rank + reorder (bucket-major)
        unsigned rec = recs[i];
        int buk = rec >> 24;
        int rank = atomicAdd(&cur4[wave][buk], 1);
        sorted[hist4[wave][buk] + rank] = rec;
    }
    __syncthreads();
    for (int p = tid; p < m; p += 256) {            // coalesced-run writes
        unsigned rec = sorted[p];
        int buk = rec >> 24;
        edge_buf[(size_t)buk * BUK_CAP + gbase[buk] + (p - hist4[0][buk])] = rec;
    }
}

// P2: one block per bucket; inline scan of bucket_cnt (no separate kernel / buffer).
__global__ __launch_bounds__(256) void finalize_csr(const unsigned* __restrict__ edge_buf,
                                                    const int* __restrict__ bucket_cnt,
                                                    int* __restrict__ rowptr,
                                                    float* __restrict__ invdeg,
                                                    unsigned short* __restrict__ csr_col) {
    __shared__ int hist[256], excl[256], cur[256], scan[256];
    int b = blockIdx.x;
    int tid = threadIdx.x;
    // inline exclusive scan over all bucket counts (cheap, removes scan kernel)
    scan[tid] = (tid < NBUK) ? bucket_cnt[tid] : 0;
    __syncthreads();
    for (int off = 1; off < 256; off <<= 1) {
        int v = (tid >= off) ? scan[tid - off] : 0;
        __syncthreads();
        scan[tid] += v;
        __syncthreads();
    }
    int cnt = bucket_cnt[b];
    int base = (b == 0) ? 0 : scan[b - 1];
    const unsigned* src = edge_buf + (size_t)b * BUK_CAP;
    __syncthreads();
    hist[tid] = 0; cur[tid] = 0;
    __syncthreads();
    for (int i = tid; i < cnt; i += 256)
        atomicAdd(&hist[(src[i] >> 16) & 255], 1);
    __syncthreads();
    scan[tid] = hist[tid];
    __syncthreads();
    for (int off = 1; off < 256; off <<= 1) {
        int v = (tid >= off) ? scan[tid - off] : 0;
        __syncthreads();
        scan[tid] += v;
        __syncthreads();
    }
    excl[tid] = (tid == 0) ? 0 : scan[tid - 1];
    __syncthreads();
    int r = b * 256 + tid;
    if (r < N_NODES) {
        rowptr[r] = base + excl[tid];
        invdeg[r] = 1.0f / (float)(hist[tid] + 1);   // +1: self loop
    }
    if (b == NBUK - 1 && tid == 0) rowptr[N_NODES] = base + cnt;
    for (int i = tid; i < cnt; i += 256) {
        unsigned rec = src[i];
        int rl = (rec >> 16) & 255;
        int pos = excl[rl] + atomicAdd(&cur[rl], 1);
        csr_col[base + pos] = (unsigned short)(rec & 0xFFFFu);
    }
}

// ---------------------------------------------------------------- converts

// x f32 [N][128] -> half-row packed bf16x2: xb[half(2)][node][32 u32]
__global__ __launch_bounds__(256) void convert_x(const float* __restrict__ x,
                                                 unsigned* __restrict__ xb) {
    int i = blockIdx.x * 256 + threadIdx.x;
    if (i < N_NODES * 64) {
        int n = i >> 6, pp = i & 63;
        int h = pp >> 5, pl = pp & 31;
        float2 v = ((const float2*)x)[i];
        xb[((size_t)h * N_NODES + n) * HALF_U + pl] =
            (unsigned)f2bf(v.x) | ((unsigned)f2bf(v.y) << 16);
    }
}

// w1 f32 [128][512] -> bf16 pre-swizzled to MFMA B-frag order: [t(32)][s(4)][lane(64)][j(8)]
__global__ __launch_bounds__(256) void make_w1p(const float* __restrict__ w1,
                                                unsigned short* __restrict__ w1p) {
    int i = blockIdx.x * 256 + threadIdx.x;     // 65536 total
    int j = i & 7, lane = (i >> 3) & 63, s = (i >> 9) & 3, t = i >> 11;
    int k = s * 32 + (lane >> 4) * 8 + j;
    int n = t * 16 + (lane & 15);
    w1p[i] = f2bf(w1[(size_t)k * D_H + n]);
}

// fold_w (blocks 0..32): wcomb = w2 @ wc, bcomb = b2 @ wc + bc.
// block 33: graph_counts (batch sorted -> binary search), merged to save a launch.
__global__ __launch_bounds__(256) void fold_w(const float* __restrict__ w2,
                                              const float* __restrict__ wc,
                                              const float* __restrict__ b2,
                                              const float* __restrict__ bc,
                                              const int* __restrict__ batch,
                                              float* __restrict__ wcomb,
                                              float* __restrict__ bcomb,
                                              int* __restrict__ gcnt) {
    int tid = threadIdx.x;
    if (blockIdx.x == 33) {
        if (tid < N_GRAPHS) {
            int g = tid;
            int lo = 0, hi = N_NODES;
            while (lo < hi) { int mid = (lo + hi) >> 1; if (batch[mid] < g) lo = mid + 1; else hi = mid; }
            int a = lo;
            lo = 0; hi = N_NODES;
            while (lo < hi) { int mid = (lo + hi) >> 1; if (batch[mid] < g + 1) lo = mid + 1; else hi = mid; }
            gcnt[g] = lo - a;
        }
        return;
    }
    int o = tid & 15, kl = tid >> 4;
    int k = blockIdx.x * 16 + kl;
    if (k > D_H) return;
    const float* wr = (k < D_H) ? (w2 + (size_t)k * D_H) : b2;
    float s = 0.f;
    for (int j = 0; j < D_H; j += 4) {
        s += wr[j + 0] * wc[(j + 0) * D_OUT + o]
           + wr[j + 1] * wc[(j + 1) * D_OUT + o]
           + wr[j + 2] * wc[(j + 2) * D_OUT + o]
           + wr[j + 3] * wc[(j + 3) * D_OUT + o];
    }
    if (k < D_H) wcomb[k * D_OUT + o] = s;
    else         bcomb[o] = s + bc[o];
}

// ---------------------------------------------------------------- propagation (bf16, half-rows)
// One ROW per WAVE (uniform trips, no divergence). 128B half-rows: per-pass gather
// footprint 6.4 MB (vs 12.8) -> higher L2 hit. Lane = (pair = lane>>5, l = u32 slot).
// shfl index j+2q+pair has exactly 2 distinct values -> 2-way bpermute broadcast = free.
// 16 independent gathers in flight (each serving 2 edges) = R11-level MLP.

__global__ __launch_bounds__(256) void propagate_half(const unsigned* __restrict__ xin,
                                                      unsigned* __restrict__ xout,
                                                      const int* __restrict__ rowptr,
                                                      const unsigned short* __restrict__ csr_col,
                                                      const float* __restrict__ invdeg) {
    int wave = threadIdx.x >> 6;
    int lane = threadIdx.x & 63;
    int pair = lane >> 5;              // which of 2 concurrent edges
    int l = lane & 31;                 // u32 slot within 128B half-row
    int r = blockIdx.x * 4 + wave;
    if (r >= N_NODES) return;
    const unsigned* xc = xin + (size_t)blockIdx.y * ((size_t)N_NODES * HALF_U);
    unsigned*       oc = xout + (size_t)blockIdx.y * ((size_t)N_NODES * HALF_U);
    int beg = rowptr[r], end = rowptr[r + 1];
    unsigned su = xc[(size_t)r * HALF_U + l];     // self loop (counted once: pair 0)
    float acc0 = (pair == 0) ? __uint_as_float(su << 16) : 0.f;
    float acc1 = (pair == 0) ? __uint_as_float(su & 0xffff0000u) : 0.f;
    for (int cs = beg; cs < end; cs += 64) {
        int nn = end - cs; if (nn > 64) nn = 64;
        int colv = (int)csr_col[cs + (lane < nn ? lane : 0)];
        int j = 0;
        for (; j + 32 <= nn; j += 32) {           // 16 gathers in flight, 32 edges
            unsigned uu[16];
#pragma unroll
            for (int q = 0; q < 16; ++q) {
                int c = __shfl(colv, j + 2 * q + pair, 64);
                uu[q] = xc[(size_t)c * HALF_U + l];
            }
#pragma unroll
            for (int q = 0; q < 16; ++q) {
                acc0 += __uint_as_float(uu[q] << 16);
                acc1 += __uint_as_float(uu[q] & 0xffff0000u);
            }
        }
        for (; j + 8 <= nn; j += 8) {             // mid tail: 4 loads, 8 edges
            unsigned uu[4];
#pragma unroll
            for (int q = 0; q < 4; ++q) {
                int c = __shfl(colv, j + 2 * q + pair, 64);
                uu[q] = xc[(size_t)c * HALF_U + l];
            }
#pragma unroll
            for (int q = 0; q < 4; ++q) {
                acc0 += __uint_as_float(uu[q] << 16);
                acc1 += __uint_as_float(uu[q] & 0xffff0000u);
            }
        }
        for (; j < nn; j += 2) {                  // predicated 2-edge tail
            int e = j + pair;
            int c = __shfl(colv, e < nn ? e : j, 64);
            unsigned u = xc[(size_t)c * HALF_U + l];
            if (e >= nn) u = 0u;
            acc0 += __uint_as_float(u << 16);
            acc1 += __uint_as_float(u & 0xffff0000u);
        }
    }
    acc0 += __shfl_xor(acc0, 32, 64);             // combine the 2 pair partials
    acc1 += __shfl_xor(acc1, 32, 64);
    float inv = invdeg[r];
    if (pair == 0)
        oc[(size_t)r * HALF_U + l] =
            (unsigned)f2bf(acc0 * inv) | ((unsigned)f2bf(acc1 * inv) << 16);
}

// ---------------------------------------------------------------- MFMA GEMM (h3 @ w1) + bias + ReLU + segmented pool
// h3 in half-row layout: K-step s = features 32s..32s+31 -> half s>>1, u32 off (s&1)*16+quad*4.

__global__ __launch_bounds__(256) void gemm_mfma_pool(const unsigned* __restrict__ h3u,
                                                      const unsigned short* __restrict__ w1p,
                                                      const float* __restrict__ b1,
                                                      const int* __restrict__ batch,
                                                      float* __restrict__ gsum) {
    __shared__ float hls[64][132];   // +4 pad: conflict-free row-strided writes
    __shared__ int bls[64];
    int tid = threadIdx.x;
    int lane = tid & 63, wave = tid >> 6;
    int quad = lane >> 4, l15 = lane & 15;
    int mbase = blockIdx.x * 64;
    int nbase = blockIdx.y * 128;

    int m = mbase + wave * 16 + l15;
    int mc = m < N_NODES ? m : N_NODES - 1;          // clamp; garbage rows skipped in epilogue
    bf16x8 afrag[4];
#pragma unroll
    for (int s = 0; s < 4; ++s)
        afrag[s] = *(const bf16x8*)(h3u + ((size_t)(s >> 1) * N_NODES + mc) * HALF_U
                                    + (s & 1) * 16 + quad * 4);

    f32x4 acc[8];
#pragma unroll
    for (int t = 0; t < 8; ++t) acc[t] = (f32x4){0.f, 0.f, 0.f, 0.f};

    const unsigned short* bbase = w1p + ((size_t)(blockIdx.y * 8) * 4 * 64 + lane) * 8;
#pragma unroll
    for (int t = 0; t < 8; ++t) {
#pragma unroll
        for (int s = 0; s < 4; ++s) {
            bf16x8 bfrag = *(const bf16x8*)(bbase + (size_t)(t * 4 + s) * 64 * 8);
            acc[t] = __builtin_amdgcn_mfma_f32_16x16x32_bf16(afrag[s], bfrag, acc[t], 0, 0, 0);
        }
    }

    if (tid < 64) {
        int mm = mbase + tid;
        bls[tid] = (mm < N_NODES) ? batch[mm] : 0;
    }
#pragma unroll
    for (int t = 0; t < 8; ++t)
#pragma unroll
        for (int rg = 0; rg < 4; ++rg)
            hls[wave * 16 + quad * 4 + rg][t * 16 + l15] = acc[t][rg];
    __syncthreads();

    // epilogue: bias + relu + sorted-segment pool; thread owns (col, 32-row half)
    int c = tid & 127, half = tid >> 7;
    float bias = b1[nbase + c];
    int r0 = half * 32;
    int cur = bls[r0];
    float s = 0.f;
    for (int r = r0; r < r0 + 32; ++r) {
        int mm = mbase + r;
        if (mm >= N_NODES) break;
        int g = bls[r];
        float v = hls[r][c] + bias;
        v = v > 0.f ? v : 0.f;
        if (g != cur) { atomicAdd(&gsum[cur * D_H + nbase + c], s); s = 0.f; cur = g; }
        s += v;
    }
    atomicAdd(&gsum[cur * D_H + nbase + c], s);
}

// ---------------------------------------------------------------- final: mean + folded (512x16) projection

__global__ __launch_bounds__(256) void final_pool(const float* __restrict__ gsum,
                                                  const int* __restrict__ gcnt,
                                                  const float* __restrict__ wcomb,
                                                  const float* __restrict__ bcomb,
                                                  float* __restrict__ out) {
    int g = blockIdx.x;
    int tid = threadIdx.x;
    __shared__ float p[D_H];
    __shared__ float part[16][17];
    int c = gcnt[g]; if (c < 1) c = 1;
    float inv = 1.0f / (float)c;
    p[tid] = gsum[g * D_H + tid] * inv;
    p[tid + 256] = gsum[g * D_H + tid + 256] * inv;
    __syncthreads();
    int o = tid & 15, ch = tid >> 4;
    int k0 = ch * 32;
    float s = 0.f;
    for (int k = k0; k < k0 + 32; ++k)
        s += p[k] * wcomb[k * D_OUT + o];
    part[ch][o] = s;
    __syncthreads();
    if (tid < D_OUT) {
        float t = bcomb[tid];
        for (int ch2 = 0; ch2 < 16; ++ch2) t += part[ch2][tid];
        out[g * D_OUT + tid] = t;
    }
}

// ---------------------------------------------------------------- launch

extern "C" void kernel_launch(void* const* d_in, const int* in_sizes, int n_in,
                              void* d_out, int out_size, void* d_ws, size_t ws_size,
                              hipStream_t stream) {
    const float* x     = (const float*)d_in[0];
    const int*   eidx  = (const int*)d_in[1];   // [2, E]
    const int*   batch = (const int*)d_in[2];
    const float* w1    = (const float*)d_in[3];
    const float* b1    = (const float*)d_in[4];
    const float* w2    = (const float*)d_in[5];
    const float* b2    = (const float*)d_in[6];
    const float* wc    = (const float*)d_in[7];
    const float* bc    = (const float*)d_in[8];
    float* out = (float*)d_out;
    const int* row = eidx;
    const int* col = eidx + N_EDGES;

    char* p = (char*)d_ws;
    auto alloc = [&](size_t bytes) { char* q = p; p += (bytes + 255) & ~(size_t)255; return q; };
    // zero-init region: bucket_cnt, gsum contiguous -> ONE memset
    char* zbase = p;
    int*   bucket_cnt = (int*)alloc((size_t)NBUK * 4);
    float* gsum       = (float*)alloc((size_t)N_GRAPHS * D_H * 4);
    size_t zbytes = (size_t)(p - zbase);
    int*   rowptr  = (int*)alloc((size_t)(N_NODES + 1) * 4);
    int*   gcnt    = (int*)alloc((size_t)N_GRAPHS * 4);
    float* invdeg  = (float*)alloc((size_t)N_NODES * 4);
    float* wcomb   = (float*)alloc((size_t)D_H * D_OUT * 4);
    float* bcomb   = (float*)alloc((size_t)D_OUT * 4);
    unsigned* edge_buf = (unsigned*)alloc((size_t)NBUK * BUK_CAP * 4);
    unsigned short* csr_col = (unsigned short*)alloc((size_t)N_EDGES * 2);
    unsigned* xb   = (unsigned*)alloc((size_t)N_NODES * 64 * 4);   // half-row bf16x2
    unsigned* h0b  = (unsigned*)alloc((size_t)N_NODES * 64 * 4);
    unsigned* h1b  = (unsigned*)alloc((size_t)N_NODES * 64 * 4);
    unsigned short* w1p = (unsigned short*)alloc((size_t)D_IN * D_H * 2);

    (void)hipMemsetAsync(zbase, 0, zbytes, stream);

    convert_x<<<(N_NODES * 64 + 255) / 256, 256, 0, stream>>>(x, xb);
    make_w1p<<<(D_IN * D_H) / 256, 256, 0, stream>>>(w1, w1p);
    fold_w<<<34, 256, 0, stream>>>(w2, wc, b2, bc, batch, wcomb, bcomb, gcnt);

    partition_edges<<<P1_BLOCKS, 256, 0, stream>>>(row, col, bucket_cnt, edge_buf);
    finalize_csr<<<NBUK, 256, 0, stream>>>(edge_buf, bucket_cnt, rowptr, invdeg, csr_col);

    dim3 pgrid((N_NODES + 3) / 4, 2);
    propagate_half<<<pgrid, 256, 0, stream>>>(xb,  h0b, rowptr, csr_col, invdeg);
    propagate_half<<<pgrid, 256, 0, stream>>>(h0b, h1b, rowptr, csr_col, invdeg);
    propagate_half<<<pgrid, 256, 0, stream>>>(h1b, h0b, rowptr, csr_col, invdeg);

    dim3 ggrid((N_NODES + 63) / 64, D_H / 128);
    gemm_mfma_pool<<<ggrid, 256, 0, stream>>>(h0b, w1p, b1, batch, gsum);
    final_pool<<<N_GRAPHS, 256, 0, stream>>>(gsum, gcnt, wcomb, bcomb, out);
}

// Round 13
// 330.127 us; speedup vs baseline: 1.0854x; 1.0854x over previous
//
#include <hip/hip_runtime.h>
#include <hip/hip_bf16.h>

#define N_NODES 50000
#define N_EDGES 1600000
#define N_GRAPHS 64
#define D_IN 128
#define D_H 512
#define D_OUT 16

// atomic-free CSR build: buckets of 256 rows
#define NBUK 196                      // ceil(50000/256)
#define BUK_CAP 9216                  // per-bucket capacity: mean 8192 + ~11 sigma
#define P1_EDGES 8192                 // edges per partition block
#define P1_BLOCKS ((N_EDGES + P1_EDGES - 1) / P1_EDGES)   // 196

typedef short bf16x8 __attribute__((ext_vector_type(8)));
typedef float f32x4 __attribute__((ext_vector_type(4)));

static __device__ __forceinline__ unsigned short f2bf(float f) {
    __hip_bfloat16 h = __float2bfloat16(f);   // RNE
    return *(unsigned short*)&h;
}

// ---------------------------------------------------------------- CSR build (atomic-free)
// P1 with per-wave sub-histograms: 4x less LDS-atomic contention than single hist.

__global__ __launch_bounds__(256) void partition_edges(const int* __restrict__ row,
                                                       const int* __restrict__ col,
                                                       int* __restrict__ bucket_cnt,
                                                       unsigned* __restrict__ edge_buf) {
    __shared__ unsigned recs[P1_EDGES];     // 32 KB
    __shared__ unsigned sorted[P1_EDGES];   // 32 KB
    __shared__ int hist4[4][NBUK];          // per-wave counts -> per-wave local bases
    __shared__ int cur4[4][NBUK];
    __shared__ int gbase[NBUK];
    __shared__ int scan[256];
    int tid = threadIdx.x;
    int wave = tid >> 6;
    int e0 = blockIdx.x * P1_EDGES;
    int m = N_EDGES - e0; if (m > P1_EDGES) m = P1_EDGES;

    for (int i = tid; i < 4 * NBUK; i += 256) ((int*)hist4)[i] = 0;
    for (int i = tid; i < 4 * NBUK; i += 256) ((int*)cur4)[i] = 0;
    __syncthreads();
    for (int i = tid; i < m; i += 256) {
        int r = row[e0 + i];
        int c = col[e0 + i];
        int buk = r >> 8;
        recs[i] = ((unsigned)buk << 24) | ((unsigned)(r & 255) << 16) | (unsigned)c;
        atomicAdd(&hist4[wave][buk], 1);
    }
    __syncthreads();
    int tot = 0;
    if (tid < NBUK) tot = hist4[0][tid] + hist4[1][tid] + hist4[2][tid] + hist4[3][tid];
    scan[tid] = (tid < NBUK) ? tot : 0;
    __syncthreads();
    for (int off = 1; off < 256; off <<= 1) {
        int v = (tid >= off) ? scan[tid - off] : 0;
        __syncthreads();
        scan[tid] += v;
        __syncthreads();
    }
    if (tid < NBUK) {
        int run = (tid == 0) ? 0 : scan[tid - 1];   // block-local excl base
        gbase[tid] = (tot > 0) ? atomicAdd(&bucket_cnt[tid], tot) : 0;  // reserve range
#pragma unroll
        for (int w = 0; w < 4; ++w) {               // per-wave local bases
            int c = hist4[w][tid];
            hist4[w][tid] = run;
            run += c;
        }
    }
    __syncthreads();
    for (int i = tid; i < m; i += 256) {            // rank + reorder (bucket-major)
        unsigned rec = recs[i];
        int buk = rec >> 24;
        int rank = atomicAdd(&cur4[wave][buk], 1);
        sorted[hist4[wave][buk] + rank] = rec;
    }
    __syncthreads();
    for (int p = tid; p < m; p += 256) {            // coalesced-run writes
        unsigned rec = sorted[p];
        int buk = rec >> 24;
        edge_buf[(size_t)buk * BUK_CAP + gbase[buk] + (p - hist4[0][buk])] = rec;
    }
}

// P2: one block per bucket; inline scan of bucket_cnt (no separate kernel / buffer).
__global__ __launch_bounds__(256) void finalize_csr(const unsigned* __restrict__ edge_buf,
                                                    const int* __restrict__ bucket_cnt,
                                                    int* __restrict__ rowptr,
                                                    float* __restrict__ invdeg,
                                                    unsigned short* __restrict__ csr_col) {
    __shared__ int hist[256], excl[256], cur[256], scan[256];
    int b = blockIdx.x;
    int tid = threadIdx.x;
    // inline exclusive scan over all bucket counts (cheap, removes scan kernel)
    scan[tid] = (tid < NBUK) ? bucket_cnt[tid] : 0;
    __syncthreads();
    for (int off = 1; off < 256; off <<= 1) {
        int v = (tid >= off) ? scan[tid - off] : 0;
        __syncthreads();
        scan[tid] += v;
        __syncthreads();
    }
    int cnt = bucket_cnt[b];
    int base = (b == 0) ? 0 : scan[b - 1];
    const unsigned* src = edge_buf + (size_t)b * BUK_CAP;
    __syncthreads();
    hist[tid] = 0; cur[tid] = 0;
    __syncthreads();
    for (int i = tid; i < cnt; i += 256)
        atomicAdd(&hist[(src[i] >> 16) & 255], 1);
    __syncthreads();
    scan[tid] = hist[tid];
    __syncthreads();
    for (int off = 1; off < 256; off <<= 1) {
        int v = (tid >= off) ? scan[tid - off] : 0;
        __syncthreads();
        scan[tid] += v;
        __syncthreads();
    }
    excl[tid] = (tid == 0) ? 0 : scan[tid - 1];
    __syncthreads();
    int r = b * 256 + tid;
    if (r < N_NODES) {
        rowptr[r] = base + excl[tid];
        invdeg[r] = 1.0f / (float)(hist[tid] + 1);   // +1: self loop
    }
    if (b == NBUK - 1 && tid == 0) rowptr[N_NODES] = base + cnt;
    for (int i = tid; i < cnt; i += 256) {
        unsigned rec = src[i];
        int rl = (rec >> 16) & 255;
        int pos = excl[rl] + atomicAdd(&cur[rl], 1);
        csr_col[base + pos] = (unsigned short)(rec & 0xFFFFu);
    }
}

// ---------------------------------------------------------------- converts

// x f32 [N][128] -> packed bf16x2 [N][64]  (node-major)
__global__ __launch_bounds__(256) void convert_x(const float* __restrict__ x,
                                                 unsigned* __restrict__ xb, int npairs) {
    int i = blockIdx.x * 256 + threadIdx.x;
    if (i < npairs) {
        float2 v = ((const float2*)x)[i];
        xb[i] = (unsigned)f2bf(v.x) | ((unsigned)f2bf(v.y) << 16);
    }
}

// w1 f32 [128][512] -> bf16 pre-swizzled to MFMA B-frag order: [t(32)][s(4)][lane(64)][j(8)]
__global__ __launch_bounds__(256) void make_w1p(const float* __restrict__ w1,
                                                unsigned short* __restrict__ w1p) {
    int i = blockIdx.x * 256 + threadIdx.x;     // 65536 total
    int j = i & 7, lane = (i >> 3) & 63, s = (i >> 9) & 3, t = i >> 11;
    int k = s * 32 + (lane >> 4) * 8 + j;
    int n = t * 16 + (lane & 15);
    w1p[i] = f2bf(w1[(size_t)k * D_H + n]);
}

// fold_w (blocks 0..32): wcomb = w2 @ wc, bcomb = b2 @ wc + bc.
// block 33: graph_counts (batch sorted -> binary search), merged to save a launch.
__global__ __launch_bounds__(256) void fold_w(const float* __restrict__ w2,
                                              const float* __restrict__ wc,
                                              const float* __restrict__ b2,
                                              const float* __restrict__ bc,
                                              const int* __restrict__ batch,
                                              float* __restrict__ wcomb,
                                              float* __restrict__ bcomb,
                                              int* __restrict__ gcnt) {
    int tid = threadIdx.x;
    if (blockIdx.x == 33) {
        if (tid < N_GRAPHS) {
            int g = tid;
            int lo = 0, hi = N_NODES;
            while (lo < hi) { int mid = (lo + hi) >> 1; if (batch[mid] < g) lo = mid + 1; else hi = mid; }
            int a = lo;
            lo = 0; hi = N_NODES;
            while (lo < hi) { int mid = (lo + hi) >> 1; if (batch[mid] < g + 1) lo = mid + 1; else hi = mid; }
            gcnt[g] = lo - a;
        }
        return;
    }
    int o = tid & 15, kl = tid >> 4;
    int k = blockIdx.x * 16 + kl;
    if (k > D_H) return;
    const float* wr = (k < D_H) ? (w2 + (size_t)k * D_H) : b2;
    float s = 0.f;
    for (int j = 0; j < D_H; j += 4) {
        s += wr[j + 0] * wc[(j + 0) * D_OUT + o]
           + wr[j + 1] * wc[(j + 1) * D_OUT + o]
           + wr[j + 2] * wc[(j + 2) * D_OUT + o]
           + wr[j + 3] * wc[(j + 3) * D_OUT + o];
    }
    if (k < D_H) wcomb[k * D_OUT + o] = s;
    else         bcomb[o] = s + bc[o];
}

// ---------------------------------------------------------------- propagation (bf16 storage, f32 accumulate)
// R11 proven shape: one row per wave, contiguous 256B row gathers, shfl-broadcast
// col indices, 16 gathers in flight. Change vs R11: 128-thread blocks (2 waves)
// -> intra-block degree imbalance max-of-2 instead of max-of-4; 16 wg/CU x 2
// waves still allows full 32-wave occupancy.

__global__ __launch_bounds__(128) void propagate_bf16(const unsigned* __restrict__ xin,
                                                      unsigned* __restrict__ xout,
                                                      const int* __restrict__ rowptr,
                                                      const unsigned short* __restrict__ csr_col,
                                                      const float* __restrict__ invdeg) {
    int wave = threadIdx.x >> 6;
    int lane = threadIdx.x & 63;
    int r = blockIdx.x * 2 + wave;
    if (r >= N_NODES) return;
    int beg = rowptr[r], end = rowptr[r + 1];
    unsigned u = xin[(size_t)r * 64 + lane];      // self loop
    float acc0 = __uint_as_float(u << 16);
    float acc1 = __uint_as_float(u & 0xffff0000u);
    for (int cs = beg; cs < end; cs += 64) {
        int nn = end - cs; if (nn > 64) nn = 64;
        int colv = (int)csr_col[cs + (lane < nn ? lane : 0)];
        int j = 0;
        for (; j + 16 <= nn; j += 16) {           // 16 independent 256B gathers in flight
            unsigned uu[16];
#pragma unroll
            for (int q = 0; q < 16; ++q) {
                int c = __shfl(colv, j + q, 64);
                uu[q] = xin[(size_t)c * 64 + lane];
            }
#pragma unroll
            for (int q = 0; q < 16; ++q) {
                acc0 += __uint_as_float(uu[q] << 16);
                acc1 += __uint_as_float(uu[q] & 0xffff0000u);
            }
        }
        for (; j + 4 <= nn; j += 4) {
            int c0 = __shfl(colv, j + 0, 64), c1 = __shfl(colv, j + 1, 64);
            int c2 = __shfl(colv, j + 2, 64), c3 = __shfl(colv, j + 3, 64);
            unsigned u0 = xin[(size_t)c0 * 64 + lane];
            unsigned u1 = xin[(size_t)c1 * 64 + lane];
            unsigned u2 = xin[(size_t)c2 * 64 + lane];
            unsigned u3 = xin[(size_t)c3 * 64 + lane];
            acc0 += __uint_as_float(u0 << 16) + __uint_as_float(u1 << 16)
                  + __uint_as_float(u2 << 16) + __uint_as_float(u3 << 16);
            acc1 += __uint_as_float(u0 & 0xffff0000u) + __uint_as_float(u1 & 0xffff0000u)
                  + __uint_as_float(u2 & 0xffff0000u) + __uint_as_float(u3 & 0xffff0000u);
        }
        for (; j < nn; ++j) {
            int c = __shfl(colv, j, 64);
            unsigned uu = xin[(size_t)c * 64 + lane];
            acc0 += __uint_as_float(uu << 16);
            acc1 += __uint_as_float(uu & 0xffff0000u);
        }
    }
    float inv = invdeg[r];
    acc0 *= inv; acc1 *= inv;
    xout[(size_t)r * 64 + lane] = (unsigned)f2bf(acc0) | ((unsigned)f2bf(acc1) << 16);
}

// ---------------------------------------------------------------- MFMA GEMM (h3 @ w1) + bias + ReLU + segmented pool
// block 256 = 4 waves; tile M=64, N=128; K=128 (4 steps of 32). node-major h3.

__global__ __launch_bounds__(256) void gemm_mfma_pool(const unsigned short* __restrict__ h3b,
                                                      const unsigned short* __restrict__ w1p,
                                                      const float* __restrict__ b1,
                                                      const int* __restrict__ batch,
                                                      float* __restrict__ gsum) {
    __shared__ float hls[64][132];   // +4 pad: conflict-free row-strided writes
    __shared__ int bls[64];
    int tid = threadIdx.x;
    int lane = tid & 63, wave = tid >> 6;
    int quad = lane >> 4, l15 = lane & 15;
    int mbase = blockIdx.x * 64;
    int nbase = blockIdx.y * 128;

    int m = mbase + wave * 16 + l15;
    int mc = m < N_NODES ? m : N_NODES - 1;          // clamp; garbage rows skipped in epilogue
    const unsigned short* arow = h3b + (size_t)mc * 128 + quad * 8;
    bf16x8 afrag[4];
#pragma unroll
    for (int s = 0; s < 4; ++s)
        afrag[s] = *(const bf16x8*)(arow + s * 32);

    f32x4 acc[8];
#pragma unroll
    for (int t = 0; t < 8; ++t) acc[t] = (f32x4){0.f, 0.f, 0.f, 0.f};

    const unsigned short* bbase = w1p + ((size_t)(blockIdx.y * 8) * 4 * 64 + lane) * 8;
#pragma unroll
    for (int t = 0; t < 8; ++t) {
#pragma unroll
        for (int s = 0; s < 4; ++s) {
            bf16x8 bfrag = *(const bf16x8*)(bbase + (size_t)(t * 4 + s) * 64 * 8);
            acc[t] = __builtin_amdgcn_mfma_f32_16x16x32_bf16(afrag[s], bfrag, acc[t], 0, 0, 0);
        }
    }

    if (tid < 64) {
        int mm = mbase + tid;
        bls[tid] = (mm < N_NODES) ? batch[mm] : 0;
    }
#pragma unroll
    for (int t = 0; t < 8; ++t)
#pragma unroll
        for (int rg = 0; rg < 4; ++rg)
            hls[wave * 16 + quad * 4 + rg][t * 16 + l15] = acc[t][rg];
    __syncthreads();

    // epilogue: bias + relu + sorted-segment pool; thread owns (col, 32-row half)
    int c = tid & 127, half = tid >> 7;
    float bias = b1[nbase + c];
    int r0 = half * 32;
    int cur = bls[r0];
    float s = 0.f;
    for (int r = r0; r < r0 + 32; ++r) {
        int mm = mbase + r;
        if (mm >= N_NODES) break;
        int g = bls[r];
        float v = hls[r][c] + bias;
        v = v > 0.f ? v : 0.f;
        if (g != cur) { atomicAdd(&gsum[cur * D_H + nbase + c], s); s = 0.f; cur = g; }
        s += v;
    }
    atomicAdd(&gsum[cur * D_H + nbase + c], s);
}

// ---------------------------------------------------------------- final: mean + folded (512x16) projection

__global__ __launch_bounds__(256) void final_pool(const float* __restrict__ gsum,
                                                  const int* __restrict__ gcnt,
                                                  const float* __restrict__ wcomb,
                                                  const float* __restrict__ bcomb,
                                                  float* __restrict__ out) {
    int g = blockIdx.x;
    int tid = threadIdx.x;
    __shared__ float p[D_H];
    __shared__ float part[16][17];
    int c = gcnt[g]; if (c < 1) c = 1;
    float inv = 1.0f / (float)c;
    p[tid] = gsum[g * D_H + tid] * inv;
    p[tid + 256] = gsum[g * D_H + tid + 256] * inv;
    __syncthreads();
    int o = tid & 15, ch = tid >> 4;
    int k0 = ch * 32;
    float s = 0.f;
    for (int k = k0; k < k0 + 32; ++k)
        s += p[k] * wcomb[k * D_OUT + o];
    part[ch][o] = s;
    __syncthreads();
    if (tid < D_OUT) {
        float t = bcomb[tid];
        for (int ch2 = 0; ch2 < 16; ++ch2) t += part[ch2][tid];
        out[g * D_OUT + tid] = t;
    }
}

// ---------------------------------------------------------------- launch

extern "C" void kernel_launch(void* const* d_in, const int* in_sizes, int n_in,
                              void* d_out, int out_size, void* d_ws, size_t ws_size,
                              hipStream_t stream) {
    const float* x     = (const float*)d_in[0];
    const int*   eidx  = (const int*)d_in[1];   // [2, E]
    const int*   batch = (const int*)d_in[2];
    const float* w1    = (const float*)d_in[3];
    const float* b1    = (const float*)d_in[4];
    const float* w2    = (const float*)d_in[5];
    const float* b2    = (const float*)d_in[6];
    const float* wc    = (const float*)d_in[7];
    const float* bc    = (const float*)d_in[8];
    float* out = (float*)d_out;
    const int* row = eidx;
    const int* col = eidx + N_EDGES;

    char* p = (char*)d_ws;
    auto alloc = [&](size_t bytes) { char* q = p; p += (bytes + 255) & ~(size_t)255; return q; };
    // zero-init region: bucket_cnt, gsum contiguous -> ONE memset
    char* zbase = p;
    int*   bucket_cnt = (int*)alloc((size_t)NBUK * 4);
    float* gsum       = (float*)alloc((size_t)N_GRAPHS * D_H * 4);
    size_t zbytes = (size_t)(p - zbase);
    int*   rowptr  = (int*)alloc((size_t)(N_NODES + 1) * 4);
    int*   gcnt    = (int*)alloc((size_t)N_GRAPHS * 4);
    float* invdeg  = (float*)alloc((size_t)N_NODES * 4);
    float* wcomb   = (float*)alloc((size_t)D_H * D_OUT * 4);
    float* bcomb   = (float*)alloc((size_t)D_OUT * 4);
    unsigned* edge_buf = (unsigned*)alloc((size_t)NBUK * BUK_CAP * 4);
    unsigned short* csr_col = (unsigned short*)alloc((size_t)N_EDGES * 2);
    unsigned* xb   = (unsigned*)alloc((size_t)N_NODES * 64 * 4);   // bf16x2 packed, node-major
    unsigned* h0b  = (unsigned*)alloc((size_t)N_NODES * 64 * 4);
    unsigned* h1b  = (unsigned*)alloc((size_t)N_NODES * 64 * 4);
    unsigned short* w1p = (unsigned short*)alloc((size_t)D_IN * D_H * 2);

    (void)hipMemsetAsync(zbase, 0, zbytes, stream);

    convert_x<<<(N_NODES * 64 + 255) / 256, 256, 0, stream>>>(x, xb, N_NODES * 64);
    make_w1p<<<(D_IN * D_H) / 256, 256, 0, stream>>>(w1, w1p);
    fold_w<<<34, 256, 0, stream>>>(w2, wc, b2, bc, batch, wcomb, bcomb, gcnt);

    partition_edges<<<P1_BLOCKS, 256, 0, stream>>>(row, col, bucket_cnt, edge_buf);
    finalize_csr<<<NBUK, 256, 0, stream>>>(edge_buf, bucket_cnt, rowptr, invdeg, csr_col);

    propagate_bf16<<<(N_NODES + 1) / 2, 128, 0, stream>>>(xb,  h0b, rowptr, csr_col, invdeg);
    propagate_bf16<<<(N_NODES + 1) / 2, 128, 0, stream>>>(h0b, h1b, rowptr, csr_col, invdeg);
    propagate_bf16<<<(N_NODES + 1) / 2, 128, 0, stream>>>(h1b, h0b, rowptr, csr_col, invdeg);

    dim3 ggrid((N_NODES + 63) / 64, D_H / 128);
    gemm_mfma_pool<<<ggrid, 256, 0, stream>>>((const unsigned short*)h0b, w1p, b1, batch, gsum);
    final_pool<<<N_GRAPHS, 256, 0, stream>>>(gsum, gcnt, wcomb, bcomb, out);
}

// Round 14
// 287.948 us; speedup vs baseline: 1.2444x; 1.1465x over previous
//
#include <hip/hip_runtime.h>
#include <hip/hip_bf16.h>
#include <hip/hip_fp8.h>

#define N_NODES 50000
#define N_EDGES 1600000
#define N_GRAPHS 64
#define D_IN 128
#define D_H 512
#define D_OUT 16

// atomic-free CSR build: buckets of 256 rows
#define NBUK 196                      // ceil(50000/256)
#define BUK_CAP 9216                  // per-bucket capacity: mean 8192 + ~11 sigma
#define P1_EDGES 8192                 // edges per partition block
#define P1_BLOCKS ((N_EDGES + P1_EDGES - 1) / P1_EDGES)   // 196

typedef short bf16x8 __attribute__((ext_vector_type(8)));
typedef float f32x4 __attribute__((ext_vector_type(4)));

static __device__ __forceinline__ unsigned short f2bf(float f) {
    __hip_bfloat16 h = __float2bfloat16(f);   // RNE
    return *(unsigned short*)&h;
}

static __device__ __forceinline__ float2 fp8x2_dec(unsigned short u) {
    __hip_fp8x2_e4m3 p;
    p.__x = (__hip_fp8x2_storage_t)u;
    return static_cast<float2>(p);
}

static __device__ __forceinline__ unsigned short fp8x2_enc(float a, float b) {
    __hip_fp8_e4m3 pa(a), pb(b);
    return (unsigned short)((unsigned)pa.__x | ((unsigned)pb.__x << 8));
}

// ---------------------------------------------------------------- CSR build (atomic-free)
// P1 with per-wave sub-histograms: 4x less LDS-atomic contention than single hist.

__global__ __launch_bounds__(256) void partition_edges(const int* __restrict__ row,
                                                       const int* __restrict__ col,
                                                       int* __restrict__ bucket_cnt,
                                                       unsigned* __restrict__ edge_buf) {
    __shared__ unsigned recs[P1_EDGES];     // 32 KB
    __shared__ unsigned sorted[P1_EDGES];   // 32 KB
    __shared__ int hist4[4][NBUK];          // per-wave counts -> per-wave local bases
    __shared__ int cur4[4][NBUK];
    __shared__ int gbase[NBUK];
    __shared__ int scan[256];
    int tid = threadIdx.x;
    int wave = tid >> 6;
    int e0 = blockIdx.x * P1_EDGES;
    int m = N_EDGES - e0; if (m > P1_EDGES) m = P1_EDGES;

    for (int i = tid; i < 4 * NBUK; i += 256) ((int*)hist4)[i] = 0;
    for (int i = tid; i < 4 * NBUK; i += 256) ((int*)cur4)[i] = 0;
    __syncthreads();
    for (int i = tid; i < m; i += 256) {
        int r = row[e0 + i];
        int c = col[e0 + i];
        int buk = r >> 8;
        recs[i] = ((unsigned)buk << 24) | ((unsigned)(r & 255) << 16) | (unsigned)c;
        atomicAdd(&hist4[wave][buk], 1);
    }
    __syncthreads();
    int tot = 0;
    if (tid < NBUK) tot = hist4[0][tid] + hist4[1][tid] + hist4[2][tid] + hist4[3][tid];
    scan[tid] = (tid < NBUK) ? tot : 0;
    __syncthreads();
    for (int off = 1; off < 256; off <<= 1) {
        int v = (tid >= off) ? scan[tid - off] : 0;
        __syncthreads();
        scan[tid] += v;
        __syncthreads();
    }
    if (tid < NBUK) {
        int run = (tid == 0) ? 0 : scan[tid - 1];   // block-local excl base
        gbase[tid] = (tot > 0) ? atomicAdd(&bucket_cnt[tid], tot) : 0;  // reserve range
#pragma unroll
        for (int w = 0; w < 4; ++w) {               // per-wave local bases
            int c = hist4[w][tid];
            hist4[w][tid] = run;
            run += c;
        }
    }
    __syncthreads();
    for (int i = tid; i < m; i += 256) {            // rank + reorder (bucket-major)
        unsigned rec = recs[i];
        int buk = rec >> 24;
        int rank = atomicAdd(&cur4[wave][buk], 1);
        sorted[hist4[wave][buk] + rank] = rec;
    }
    __syncthreads();
    for (int p = tid; p < m; p += 256) {            // coalesced-run writes
        unsigned rec = sorted[p];
        int buk = rec >> 24;
        edge_buf[(size_t)buk * BUK_CAP + gbase[buk] + (p - hist4[0][buk])] = rec;
    }
}

// P2: one block per bucket; inline scan of bucket_cnt (no separate kernel / buffer).
__global__ __launch_bounds__(256) void finalize_csr(const unsigned* __restrict__ edge_buf,
                                                    const int* __restrict__ bucket_cnt,
                                                    int* __restrict__ rowptr,
                                                    float* __restrict__ invdeg,
                                                    unsigned short* __restrict__ csr_col) {
    __shared__ int hist[256], excl[256], cur[256], scan[256];
    int b = blockIdx.x;
    int tid = threadIdx.x;
    // inline exclusive scan over all bucket counts (cheap, removes scan kernel)
    scan[tid] = (tid < NBUK) ? bucket_cnt[tid] : 0;
    __syncthreads();
    for (int off = 1; off < 256; off <<= 1) {
        int v = (tid >= off) ? scan[tid - off] : 0;
        __syncthreads();
        scan[tid] += v;
        __syncthreads();
    }
    int cnt = bucket_cnt[b];
    int base = (b == 0) ? 0 : scan[b - 1];
    const unsigned* src = edge_buf + (size_t)b * BUK_CAP;
    __syncthreads();
    hist[tid] = 0; cur[tid] = 0;
    __syncthreads();
    for (int i = tid; i < cnt; i += 256)
        atomicAdd(&hist[(src[i] >> 16) & 255], 1);
    __syncthreads();
    scan[tid] = hist[tid];
    __syncthreads();
    for (int off = 1; off < 256; off <<= 1) {
        int v = (tid >= off) ? scan[tid - off] : 0;
        __syncthreads();
        scan[tid] += v;
        __syncthreads();
    }
    excl[tid] = (tid == 0) ? 0 : scan[tid - 1];
    __syncthreads();
    int r = b * 256 + tid;
    if (r < N_NODES) {
        rowptr[r] = base + excl[tid];
        invdeg[r] = 1.0f / (float)(hist[tid] + 1);   // +1: self loop
    }
    if (b == NBUK - 1 && tid == 0) rowptr[N_NODES] = base + cnt;
    for (int i = tid; i < cnt; i += 256) {
        unsigned rec = src[i];
        int rl = (rec >> 16) & 255;
        int pos = excl[rl] + atomicAdd(&cur[rl], 1);
        csr_col[base + pos] = (unsigned short)(rec & 0xFFFFu);
    }
}

// ---------------------------------------------------------------- converts

// x f32 [N][128] -> fp8 e4m3 packed x2: xf[node][64 u16]  (scale 1: x ~ N(0,1) fits e4m3)
__global__ __launch_bounds__(256) void convert_x(const float* __restrict__ x,
                                                 unsigned short* __restrict__ xf, int npairs) {
    int i = blockIdx.x * 256 + threadIdx.x;
    if (i < npairs) {
        float2 v = ((const float2*)x)[i];
        xf[i] = fp8x2_enc(v.x, v.y);
    }
}

// w1 f32 [128][512] -> bf16 pre-swizzled to MFMA B-frag order: [t(32)][s(4)][lane(64)][j(8)]
__global__ __launch_bounds__(256) void make_w1p(const float* __restrict__ w1,
                                                unsigned short* __restrict__ w1p) {
    int i = blockIdx.x * 256 + threadIdx.x;     // 65536 total
    int j = i & 7, lane = (i >> 3) & 63, s = (i >> 9) & 3, t = i >> 11;
    int k = s * 32 + (lane >> 4) * 8 + j;
    int n = t * 16 + (lane & 15);
    w1p[i] = f2bf(w1[(size_t)k * D_H + n]);
}

// fold_w (blocks 0..32): wcomb = w2 @ wc, bcomb = b2 @ wc + bc.
// block 33: graph_counts (batch sorted -> binary search), merged to save a launch.
__global__ __launch_bounds__(256) void fold_w(const float* __restrict__ w2,
                                              const float* __restrict__ wc,
                                              const float* __restrict__ b2,
                                              const float* __restrict__ bc,
                                              const int* __restrict__ batch,
                                              float* __restrict__ wcomb,
                                              float* __restrict__ bcomb,
                                              int* __restrict__ gcnt) {
    int tid = threadIdx.x;
    if (blockIdx.x == 33) {
        if (tid < N_GRAPHS) {
            int g = tid;
            int lo = 0, hi = N_NODES;
            while (lo < hi) { int mid = (lo + hi) >> 1; if (batch[mid] < g) lo = mid + 1; else hi = mid; }
            int a = lo;
            lo = 0; hi = N_NODES;
            while (lo < hi) { int mid = (lo + hi) >> 1; if (batch[mid] < g + 1) lo = mid + 1; else hi = mid; }
            gcnt[g] = lo - a;
        }
        return;
    }
    int o = tid & 15, kl = tid >> 4;
    int k = blockIdx.x * 16 + kl;
    if (k > D_H) return;
    const float* wr = (k < D_H) ? (w2 + (size_t)k * D_H) : b2;
    float s = 0.f;
    for (int j = 0; j < D_H; j += 4) {
        s += wr[j + 0] * wc[(j + 0) * D_OUT + o]
           + wr[j + 1] * wc[(j + 1) * D_OUT + o]
           + wr[j + 2] * wc[(j + 2) * D_OUT + o]
           + wr[j + 3] * wc[(j + 3) * D_OUT + o];
    }
    if (k < D_H) wcomb[k * D_OUT + o] = s;
    else         bcomb[o] = s + bc[o];
}

// ---------------------------------------------------------------- propagation (fp8 storage, f32 accumulate)
// R13's proven execution shape (one row per wave, full-wave contiguous row gather,
// shfl-broadcast indices, 16 gathers in flight) but fp8 rows: 128 B = 64 lanes x u16
// -> 2 cache lines/edge (vs 4) and a 6.4 MB working set (vs 12.8). Decode is 1 HW
// cvt per pair. Each fp8 store applies x8 scale (values shrink ~sqrt(34)/hop; keeps
// them out of e4m3 subnormals); hop 3 divides by 64 and emits bf16 node-major.

__global__ __launch_bounds__(128) void propagate_fp8(const unsigned short* __restrict__ xin,
                                                     unsigned short* __restrict__ out8,
                                                     unsigned* __restrict__ out16,
                                                     int last, float extra,
                                                     const int* __restrict__ rowptr,
                                                     const unsigned short* __restrict__ csr_col,
                                                     const float* __restrict__ invdeg) {
    int wave = threadIdx.x >> 6;
    int lane = threadIdx.x & 63;
    int r = blockIdx.x * 2 + wave;
    if (r >= N_NODES) return;
    int beg = rowptr[r], end = rowptr[r + 1];
    float2 sv = fp8x2_dec(xin[(size_t)r * 64 + lane]);   // self loop
    float acc0 = sv.x, acc1 = sv.y;
    for (int cs = beg; cs < end; cs += 64) {
        int nn = end - cs; if (nn > 64) nn = 64;
        int colv = (int)csr_col[cs + (lane < nn ? lane : 0)];
        int j = 0;
        for (; j + 16 <= nn; j += 16) {           // 16 independent 128B gathers in flight
            unsigned short uu[16];
#pragma unroll
            for (int q = 0; q < 16; ++q) {
                int c = __shfl(colv, j + q, 64);
                uu[q] = xin[(size_t)c * 64 + lane];
            }
#pragma unroll
            for (int q = 0; q < 16; ++q) {
                float2 v = fp8x2_dec(uu[q]);
                acc0 += v.x; acc1 += v.y;
            }
        }
        for (; j + 4 <= nn; j += 4) {
            unsigned short u0, u1, u2, u3;
            {
                int c0 = __shfl(colv, j + 0, 64), c1 = __shfl(colv, j + 1, 64);
                int c2 = __shfl(colv, j + 2, 64), c3 = __shfl(colv, j + 3, 64);
                u0 = xin[(size_t)c0 * 64 + lane];
                u1 = xin[(size_t)c1 * 64 + lane];
                u2 = xin[(size_t)c2 * 64 + lane];
                u3 = xin[(size_t)c3 * 64 + lane];
            }
            float2 v0 = fp8x2_dec(u0), v1 = fp8x2_dec(u1);
            float2 v2 = fp8x2_dec(u2), v3 = fp8x2_dec(u3);
            acc0 += v0.x + v1.x + v2.x + v3.x;
            acc1 += v0.y + v1.y + v2.y + v3.y;
        }
        for (; j < nn; ++j) {
            int c = __shfl(colv, j, 64);
            float2 v = fp8x2_dec(xin[(size_t)c * 64 + lane]);
            acc0 += v.x; acc1 += v.y;
        }
    }
    float s = invdeg[r] * extra;
    acc0 *= s; acc1 *= s;
    if (last) {
        out16[(size_t)r * 64 + lane] = (unsigned)f2bf(acc0) | ((unsigned)f2bf(acc1) << 16);
    } else {
        out8[(size_t)r * 64 + lane] = fp8x2_enc(acc0, acc1);
    }
}

// ---------------------------------------------------------------- MFMA GEMM (h3 @ w1) + bias + ReLU + segmented pool
// block 256 = 4 waves; tile M=64, N=128; K=128 (4 steps of 32). node-major bf16 h3.

__global__ __launch_bounds__(256) void gemm_mfma_pool(const unsigned short* __restrict__ h3b,
                                                      const unsigned short* __restrict__ w1p,
                                                      const float* __restrict__ b1,
                                                      const int* __restrict__ batch,
                                                      float* __restrict__ gsum) {
    __shared__ float hls[64][132];   // +4 pad: conflict-free row-strided writes
    __shared__ int bls[64];
    int tid = threadIdx.x;
    int lane = tid & 63, wave = tid >> 6;
    int quad = lane >> 4, l15 = lane & 15;
    int mbase = blockIdx.x * 64;
    int nbase = blockIdx.y * 128;

    int m = mbase + wave * 16 + l15;
    int mc = m < N_NODES ? m : N_NODES - 1;          // clamp; garbage rows skipped in epilogue
    const unsigned short* arow = h3b + (size_t)mc * 128 + quad * 8;
    bf16x8 afrag[4];
#pragma unroll
    for (int s = 0; s < 4; ++s)
        afrag[s] = *(const bf16x8*)(arow + s * 32);

    f32x4 acc[8];
#pragma unroll
    for (int t = 0; t < 8; ++t) acc[t] = (f32x4){0.f, 0.f, 0.f, 0.f};

    const unsigned short* bbase = w1p + ((size_t)(blockIdx.y * 8) * 4 * 64 + lane) * 8;
#pragma unroll
    for (int t = 0; t < 8; ++t) {
#pragma unroll
        for (int s = 0; s < 4; ++s) {
            bf16x8 bfrag = *(const bf16x8*)(bbase + (size_t)(t * 4 + s) * 64 * 8);
            acc[t] = __builtin_amdgcn_mfma_f32_16x16x32_bf16(afrag[s], bfrag, acc[t], 0, 0, 0);
        }
    }

    if (tid < 64) {
        int mm = mbase + tid;
        bls[tid] = (mm < N_NODES) ? batch[mm] : 0;
    }
#pragma unroll
    for (int t = 0; t < 8; ++t)
#pragma unroll
        for (int rg = 0; rg < 4; ++rg)
            hls[wave * 16 + quad * 4 + rg][t * 16 + l15] = acc[t][rg];
    __syncthreads();

    // epilogue: bias + relu + sorted-segment pool; thread owns (col, 32-row half)
    int c = tid & 127, half = tid >> 7;
    float bias = b1[nbase + c];
    int r0 = half * 32;
    int cur = bls[r0];
    float s = 0.f;
    for (int r = r0; r < r0 + 32; ++r) {
        int mm = mbase + r;
        if (mm >= N_NODES) break;
        int g = bls[r];
        float v = hls[r][c] + bias;
        v = v > 0.f ? v : 0.f;
        if (g != cur) { atomicAdd(&gsum[cur * D_H + nbase + c], s); s = 0.f; cur = g; }
        s += v;
    }
    atomicAdd(&gsum[cur * D_H + nbase + c], s);
}

// ---------------------------------------------------------------- final: mean + folded (512x16) projection

__global__ __launch_bounds__(256) void final_pool(const float* __restrict__ gsum,
                                                  const int* __restrict__ gcnt,
                                                  const float* __restrict__ wcomb,
                                                  const float* __restrict__ bcomb,
                                                  float* __restrict__ out) {
    int g = blockIdx.x;
    int tid = threadIdx.x;
    __shared__ float p[D_H];
    __shared__ float part[16][17];
    int c = gcnt[g]; if (c < 1) c = 1;
    float inv = 1.0f / (float)c;
    p[tid] = gsum[g * D_H + tid] * inv;
    p[tid + 256] = gsum[g * D_H + tid + 256] * inv;
    __syncthreads();
    int o = tid & 15, ch = tid >> 4;
    int k0 = ch * 32;
    float s = 0.f;
    for (int k = k0; k < k0 + 32; ++k)
        s += p[k] * wcomb[k * D_OUT + o];
    part[ch][o] = s;
    __syncthreads();
    if (tid < D_OUT) {
        float t = bcomb[tid];
        for (int ch2 = 0; ch2 < 16; ++ch2) t += part[ch2][tid];
        out[g * D_OUT + tid] = t;
    }
}

// ---------------------------------------------------------------- launch

extern "C" void kernel_launch(void* const* d_in, const int* in_sizes, int n_in,
                              void* d_out, int out_size, void* d_ws, size_t ws_size,
                              hipStream_t stream) {
    const float* x     = (const float*)d_in[0];
    const int*   eidx  = (const int*)d_in[1];   // [2, E]
    const int*   batch = (const int*)d_in[2];
    const float* w1    = (const float*)d_in[3];
    const float* b1    = (const float*)d_in[4];
    const float* w2    = (const float*)d_in[5];
    const float* b2    = (const float*)d_in[6];
    const float* wc    = (const float*)d_in[7];
    const float* bc    = (const float*)d_in[8];
    float* out = (float*)d_out;
    const int* row = eidx;
    const int* col = eidx + N_EDGES;

    char* p = (char*)d_ws;
    auto alloc = [&](size_t bytes) { char* q = p; p += (bytes + 255) & ~(size_t)255; return q; };
    // zero-init region: bucket_cnt, gsum contiguous -> ONE memset
    char* zbase = p;
    int*   bucket_cnt = (int*)alloc((size_t)NBUK * 4);
    float* gsum       = (float*)alloc((size_t)N_GRAPHS * D_H * 4);
    size_t zbytes = (size_t)(p - zbase);
    int*   rowptr  = (int*)alloc((size_t)(N_NODES + 1) * 4);
    int*   gcnt    = (int*)alloc((size_t)N_GRAPHS * 4);
    float* invdeg  = (float*)alloc((size_t)N_NODES * 4);
    float* wcomb   = (float*)alloc((size_t)D_H * D_OUT * 4);
    float* bcomb   = (float*)alloc((size_t)D_OUT * 4);
    unsigned* edge_buf = (unsigned*)alloc((size_t)NBUK * BUK_CAP * 4);
    unsigned short* csr_col = (unsigned short*)alloc((size_t)N_EDGES * 2);
    unsigned short* xf  = (unsigned short*)alloc((size_t)N_NODES * 64 * 2);  // fp8x2
    unsigned short* h0f = (unsigned short*)alloc((size_t)N_NODES * 64 * 2);  // fp8x2
    unsigned short* h1f = (unsigned short*)alloc((size_t)N_NODES * 64 * 2);  // fp8x2
    unsigned* h3b  = (unsigned*)alloc((size_t)N_NODES * 64 * 4);             // bf16x2 node-major
    unsigned short* w1p = (unsigned short*)alloc((size_t)D_IN * D_H * 2);

    (void)hipMemsetAsync(zbase, 0, zbytes, stream);

    convert_x<<<(N_NODES * 64 + 255) / 256, 256, 0, stream>>>(x, xf, N_NODES * 64);
    make_w1p<<<(D_IN * D_H) / 256, 256, 0, stream>>>(w1, w1p);
    fold_w<<<34, 256, 0, stream>>>(w2, wc, b2, bc, batch, wcomb, bcomb, gcnt);

    partition_edges<<<P1_BLOCKS, 256, 0, stream>>>(row, col, bucket_cnt, edge_buf);
    finalize_csr<<<NBUK, 256, 0, stream>>>(edge_buf, bucket_cnt, rowptr, invdeg, csr_col);

    int pgrid = (N_NODES + 1) / 2;
    propagate_fp8<<<pgrid, 128, 0, stream>>>(xf,  h0f, nullptr, 0, 8.0f,
                                             rowptr, csr_col, invdeg);
    propagate_fp8<<<pgrid, 128, 0, stream>>>(h0f, h1f, nullptr, 0, 8.0f,
                                             rowptr, csr_col, invdeg);
    propagate_fp8<<<pgrid, 128, 0, stream>>>(h1f, nullptr, h3b, 1, 1.0f / 64.0f,
                                             rowptr, csr_col, invdeg);

    dim3 ggrid((N_NODES + 63) / 64, D_H / 128);
    gemm_mfma_pool<<<ggrid, 256, 0, stream>>>((const unsigned short*)h3b, w1p, b1, batch, gsum);
    final_pool<<<N_GRAPHS, 256, 0, stream>>>(gsum, gcnt, wcomb, bcomb, out);
}

// Round 15
// 266.837 us; speedup vs baseline: 1.3429x; 1.0791x over previous
//
#include <hip/hip_runtime.h>
#include <hip/hip_bf16.h>
#include <hip/hip_fp8.h>

#define N_NODES 50000
#define N_EDGES 1600000
#define N_GRAPHS 64
#define D_IN 128
#define D_H 512
#define D_OUT 16

// atomic-free CSR build: buckets of 128 rows, 391 blocks for both phases
#define NBUK 391                      // ceil(50000/128)
#define BUK_CAP 4608                  // mean 4092 + ~8 sigma
#define P1_EDGES 4096                 // edges per partition block
#define P1_BLOCKS ((N_EDGES + P1_EDGES - 1) / P1_EDGES)   // 391

typedef short bf16x8 __attribute__((ext_vector_type(8)));
typedef float f32x4 __attribute__((ext_vector_type(4)));

static __device__ __forceinline__ unsigned short f2bf(float f) {
    __hip_bfloat16 h = __float2bfloat16(f);   // RNE
    return *(unsigned short*)&h;
}

static __device__ __forceinline__ float2 fp8x2_dec(unsigned short u) {
    __hip_fp8x2_e4m3 p;
    p.__x = (__hip_fp8x2_storage_t)u;
    return static_cast<float2>(p);
}

static __device__ __forceinline__ unsigned short fp8x2_enc(float a, float b) {
    __hip_fp8_e4m3 pa(a), pb(b);
    return (unsigned short)((unsigned)pa.__x | ((unsigned)pb.__x << 8));
}

// ---------------------------------------------------------------- CSR build (atomic-free)
// P1: 391 blocks x 512 threads, 4096 edges each. rec = (buk:9)<<23 | (rlow:7)<<16 | col:16.
// Sub-histograms per wave-pair (4x) cut LDS-atomic contention.

__global__ __launch_bounds__(512) void partition_edges(const int* __restrict__ row,
                                                       const int* __restrict__ col,
                                                       int* __restrict__ bucket_cnt,
                                                       unsigned* __restrict__ edge_buf) {
    __shared__ unsigned recs[P1_EDGES];     // 16 KB
    __shared__ unsigned sorted[P1_EDGES];   // 16 KB
    __shared__ int hist4[4][NBUK];          // per-wave-pair counts -> local bases
    __shared__ int cur4[4][NBUK];
    __shared__ int gbase[NBUK];
    __shared__ int scan[512];
    int tid = threadIdx.x;
    int w2 = tid >> 7;                      // wave-pair 0..3
    int e0 = blockIdx.x * P1_EDGES;
    int m = N_EDGES - e0; if (m > P1_EDGES) m = P1_EDGES;

    for (int i = tid; i < 4 * NBUK; i += 512) ((int*)hist4)[i] = 0;
    for (int i = tid; i < 4 * NBUK; i += 512) ((int*)cur4)[i] = 0;
    __syncthreads();
    for (int i = tid; i < m; i += 512) {
        int r = row[e0 + i];
        int c = col[e0 + i];
        int buk = r >> 7;
        recs[i] = ((unsigned)buk << 23) | ((unsigned)(r & 127) << 16) | (unsigned)c;
        atomicAdd(&hist4[w2][buk], 1);
    }
    __syncthreads();
    int tot = 0;
    if (tid < NBUK) tot = hist4[0][tid] + hist4[1][tid] + hist4[2][tid] + hist4[3][tid];
    scan[tid] = (tid < NBUK) ? tot : 0;
    __syncthreads();
    for (int off = 1; off < 512; off <<= 1) {
        int v = (tid >= off) ? scan[tid - off] : 0;
        __syncthreads();
        scan[tid] += v;
        __syncthreads();
    }
    if (tid < NBUK) {
        int run = (tid == 0) ? 0 : scan[tid - 1];   // block-local excl base
        gbase[tid] = (tot > 0) ? atomicAdd(&bucket_cnt[tid], tot) : 0;  // reserve range
#pragma unroll
        for (int w = 0; w < 4; ++w) {               // per-sub-group local bases
            int c = hist4[w][tid];
            hist4[w][tid] = run;
            run += c;
        }
    }
    __syncthreads();
    for (int i = tid; i < m; i += 512) {            // rank + reorder (bucket-major)
        unsigned rec = recs[i];
        int buk = rec >> 23;
        int rank = atomicAdd(&cur4[w2][buk], 1);
        sorted[hist4[w2][buk] + rank] = rec;
    }
    __syncthreads();
    for (int p = tid; p < m; p += 512) {            // coalesced-run writes
        unsigned rec = sorted[p];
        int buk = rec >> 23;
        edge_buf[(size_t)buk * BUK_CAP + gbase[buk] + (p - hist4[0][buk])] = rec;
    }
}

// P2: one block per bucket (391 x 512); inline scan of bucket_cnt; LDS-cursor scatter
// into the bucket's contiguous csr_col (u16) window.
__global__ __launch_bounds__(512) void finalize_csr(const unsigned* __restrict__ edge_buf,
                                                    const int* __restrict__ bucket_cnt,
                                                    int* __restrict__ rowptr,
                                                    float* __restrict__ invdeg,
                                                    unsigned short* __restrict__ csr_col) {
    __shared__ int hist[128], excl[128], cur[128];
    __shared__ int scan[512];
    int b = blockIdx.x;
    int tid = threadIdx.x;
    // inline exclusive scan over all bucket counts
    scan[tid] = (tid < NBUK) ? bucket_cnt[tid] : 0;
    __syncthreads();
    for (int off = 1; off < 512; off <<= 1) {
        int v = (tid >= off) ? scan[tid - off] : 0;
        __syncthreads();
        scan[tid] += v;
        __syncthreads();
    }
    int cnt = bucket_cnt[b];
    int base = (b == 0) ? 0 : scan[b - 1];
    const unsigned* src = edge_buf + (size_t)b * BUK_CAP;
    __syncthreads();
    if (tid < 128) { hist[tid] = 0; cur[tid] = 0; }
    __syncthreads();
    for (int i = tid; i < cnt; i += 512)
        atomicAdd(&hist[(src[i] >> 16) & 127], 1);
    __syncthreads();
    scan[tid] = (tid < 128) ? hist[tid] : 0;        // 512-wide scan, first 128 valid
    __syncthreads();
    for (int off = 1; off < 512; off <<= 1) {
        int v = (tid >= off) ? scan[tid - off] : 0;
        __syncthreads();
        scan[tid] += v;
        __syncthreads();
    }
    if (tid < 128) excl[tid] = (tid == 0) ? 0 : scan[tid - 1];
    __syncthreads();
    int r = b * 128 + tid;
    if (tid < 128 && r < N_NODES) {
        rowptr[r] = base + excl[tid];
        invdeg[r] = 1.0f / (float)(hist[tid] + 1);   // +1: self loop
    }
    if (b == NBUK - 1 && tid == 0) rowptr[N_NODES] = base + cnt;
    for (int i = tid; i < cnt; i += 512) {
        unsigned rec = src[i];
        int rl = (rec >> 16) & 127;
        int pos = excl[rl] + atomicAdd(&cur[rl], 1);
        csr_col[base + pos] = (unsigned short)(rec & 0xFFFFu);
    }
}

// ---------------------------------------------------------------- merged prep
// blocks [0,12500): convert_x (f32 -> fp8x2); [12500,12756): make_w1p (bf16 B-frag
// swizzle); [12756,12790): fold_w (wcomb/bcomb) + graph_counts (last block).

__global__ __launch_bounds__(256) void prep(const float* __restrict__ x,
                                            unsigned short* __restrict__ xf,
                                            const float* __restrict__ w1,
                                            unsigned short* __restrict__ w1p,
                                            const float* __restrict__ w2,
                                            const float* __restrict__ wc,
                                            const float* __restrict__ b2,
                                            const float* __restrict__ bc,
                                            const int* __restrict__ batch,
                                            float* __restrict__ wcomb,
                                            float* __restrict__ bcomb,
                                            int* __restrict__ gcnt) {
    int b = blockIdx.x;
    int tid = threadIdx.x;
    if (b < 12500) {                                // convert_x: 12500*256 == N*64 exactly
        int i = b * 256 + tid;
        float2 v = ((const float2*)x)[i];
        xf[i] = fp8x2_enc(v.x, v.y);
        return;
    }
    if (b < 12756) {                                // make_w1p: 256 blocks, 65536 elems
        int i = (b - 12500) * 256 + tid;
        int j = i & 7, lane = (i >> 3) & 63, s = (i >> 9) & 3, t = i >> 11;
        int k = s * 32 + (lane >> 4) * 8 + j;
        int n = t * 16 + (lane & 15);
        w1p[i] = f2bf(w1[(size_t)k * D_H + n]);
        return;
    }
    int fb = b - 12756;                             // fold_w blocks 0..33
    if (fb == 33) {
        if (tid < N_GRAPHS) {
            int g = tid;
            int lo = 0, hi = N_NODES;
            while (lo < hi) { int mid = (lo + hi) >> 1; if (batch[mid] < g) lo = mid + 1; else hi = mid; }
            int a = lo;
            lo = 0; hi = N_NODES;
            while (lo < hi) { int mid = (lo + hi) >> 1; if (batch[mid] < g + 1) lo = mid + 1; else hi = mid; }
            gcnt[g] = lo - a;
        }
        return;
    }
    int o = tid & 15, kl = tid >> 4;
    int k = fb * 16 + kl;
    if (k > D_H) return;
    const float* wr = (k < D_H) ? (w2 + (size_t)k * D_H) : b2;
    float s = 0.f;
    for (int j = 0; j < D_H; j += 4) {
        s += wr[j + 0] * wc[(j + 0) * D_OUT + o]
           + wr[j + 1] * wc[(j + 1) * D_OUT + o]
           + wr[j + 2] * wc[(j + 2) * D_OUT + o]
           + wr[j + 3] * wc[(j + 3) * D_OUT + o];
    }
    if (k < D_H) wcomb[k * D_OUT + o] = s;
    else         bcomb[o] = s + bc[o];
}

// ---------------------------------------------------------------- propagation (fp8 storage, f32 accumulate)
// Proven shape: one row per wave, full-wave contiguous 128B row gather, shfl-broadcast
// indices, 16 gathers in flight. x8 scale per fp8 store (values shrink ~sqrt(34)/hop);
// hop 3 divides by 64 and emits bf16 node-major for the MFMA GEMM.

__global__ __launch_bounds__(128) void propagate_fp8(const unsigned short* __restrict__ xin,
                                                     unsigned short* __restrict__ out8,
                                                     unsigned* __restrict__ out16,
                                                     int last, float extra,
                                                     const int* __restrict__ rowptr,
                                                     const unsigned short* __restrict__ csr_col,
                                                     const float* __restrict__ invdeg) {
    int wave = threadIdx.x >> 6;
    int lane = threadIdx.x & 63;
    int r = blockIdx.x * 2 + wave;
    if (r >= N_NODES) return;
    int beg = rowptr[r], end = rowptr[r + 1];
    float2 sv = fp8x2_dec(xin[(size_t)r * 64 + lane]);   // self loop
    float acc0 = sv.x, acc1 = sv.y;
    for (int cs = beg; cs < end; cs += 64) {
        int nn = end - cs; if (nn > 64) nn = 64;
        int colv = (int)csr_col[cs + (lane < nn ? lane : 0)];
        int j = 0;
        for (; j + 16 <= nn; j += 16) {           // 16 independent 128B gathers in flight
            unsigned short uu[16];
#pragma unroll
            for (int q = 0; q < 16; ++q) {
                int c = __shfl(colv, j + q, 64);
                uu[q] = xin[(size_t)c * 64 + lane];
            }
#pragma unroll
            for (int q = 0; q < 16; ++q) {
                float2 v = fp8x2_dec(uu[q]);
                acc0 += v.x; acc1 += v.y;
            }
        }
        for (; j + 4 <= nn; j += 4) {
            unsigned short u0, u1, u2, u3;
            {
                int c0 = __shfl(colv, j + 0, 64), c1 = __shfl(colv, j + 1, 64);
                int c2 = __shfl(colv, j + 2, 64), c3 = __shfl(colv, j + 3, 64);
                u0 = xin[(size_t)c0 * 64 + lane];
                u1 = xin[(size_t)c1 * 64 + lane];
                u2 = xin[(size_t)c2 * 64 + lane];
                u3 = xin[(size_t)c3 * 64 + lane];
            }
            float2 v0 = fp8x2_dec(u0), v1 = fp8x2_dec(u1);
            float2 v2 = fp8x2_dec(u2), v3 = fp8x2_dec(u3);
            acc0 += v0.x + v1.x + v2.x + v3.x;
            acc1 += v0.y + v1.y + v2.y + v3.y;
        }
        for (; j < nn; ++j) {
            int c = __shfl(colv, j, 64);
            float2 v = fp8x2_dec(xin[(size_t)c * 64 + lane]);
            acc0 += v.x; acc1 += v.y;
        }
    }
    float s = invdeg[r] * extra;
    acc0 *= s; acc1 *= s;
    if (last) {
        out16[(size_t)r * 64 + lane] = (unsigned)f2bf(acc0) | ((unsigned)f2bf(acc1) << 16);
    } else {
        out8[(size_t)r * 64 + lane] = fp8x2_enc(acc0, acc1);
    }
}

// ---------------------------------------------------------------- MFMA GEMM (h3 @ w1) + bias + ReLU + segmented pool

__global__ __launch_bounds__(256) void gemm_mfma_pool(const unsigned short* __restrict__ h3b,
                                                      const unsigned short* __restrict__ w1p,
                                                      const float* __restrict__ b1,
                                                      const int* __restrict__ batch,
                                                      float* __restrict__ gsum) {
    __shared__ float hls[64][132];   // +4 pad: conflict-free row-strided writes
    __shared__ int bls[64];
    int tid = threadIdx.x;
    int lane = tid & 63, wave = tid >> 6;
    int quad = lane >> 4, l15 = lane & 15;
    int mbase = blockIdx.x * 64;
    int nbase = blockIdx.y * 128;

    int m = mbase + wave * 16 + l15;
    int mc = m < N_NODES ? m : N_NODES - 1;          // clamp; garbage rows skipped in epilogue
    const unsigned short* arow = h3b + (size_t)mc * 128 + quad * 8;
    bf16x8 afrag[4];
#pragma unroll
    for (int s = 0; s < 4; ++s)
        afrag[s] = *(const bf16x8*)(arow + s * 32);

    f32x4 acc[8];
#pragma unroll
    for (int t = 0; t < 8; ++t) acc[t] = (f32x4){0.f, 0.f, 0.f, 0.f};

    const unsigned short* bbase = w1p + ((size_t)(blockIdx.y * 8) * 4 * 64 + lane) * 8;
#pragma unroll
    for (int t = 0; t < 8; ++t) {
#pragma unroll
        for (int s = 0; s < 4; ++s) {
            bf16x8 bfrag = *(const bf16x8*)(bbase + (size_t)(t * 4 + s) * 64 * 8);
            acc[t] = __builtin_amdgcn_mfma_f32_16x16x32_bf16(afrag[s], bfrag, acc[t], 0, 0, 0);
        }
    }

    if (tid < 64) {
        int mm = mbase + tid;
        bls[tid] = (mm < N_NODES) ? batch[mm] : 0;
    }
#pragma unroll
    for (int t = 0; t < 8; ++t)
#pragma unroll
        for (int rg = 0; rg < 4; ++rg)
            hls[wave * 16 + quad * 4 + rg][t * 16 + l15] = acc[t][rg];
    __syncthreads();

    // epilogue: bias + relu + sorted-segment pool; thread owns (col, 32-row half)
    int c = tid & 127, half = tid >> 7;
    float bias = b1[nbase + c];
    int r0 = half * 32;
    int cur = bls[r0];
    float s = 0.f;
    for (int r = r0; r < r0 + 32; ++r) {
        int mm = mbase + r;
        if (mm >= N_NODES) break;
        int g = bls[r];
        float v = hls[r][c] + bias;
        v = v > 0.f ? v : 0.f;
        if (g != cur) { atomicAdd(&gsum[cur * D_H + nbase + c], s); s = 0.f; cur = g; }
        s += v;
    }
    atomicAdd(&gsum[cur * D_H + nbase + c], s);
}

// ---------------------------------------------------------------- final: mean + folded (512x16) projection

__global__ __launch_bounds__(256) void final_pool(const float* __restrict__ gsum,
                                                  const int* __restrict__ gcnt,
                                                  const float* __restrict__ wcomb,
                                                  const float* __restrict__ bcomb,
                                                  float* __restrict__ out) {
    int g = blockIdx.x;
    int tid = threadIdx.x;
    __shared__ float p[D_H];
    __shared__ float part[16][17];
    int c = gcnt[g]; if (c < 1) c = 1;
    float inv = 1.0f / (float)c;
    p[tid] = gsum[g * D_H + tid] * inv;
    p[tid + 256] = gsum[g * D_H + tid + 256] * inv;
    __syncthreads();
    int o = tid & 15, ch = tid >> 4;
    int k0 = ch * 32;
    float s = 0.f;
    for (int k = k0; k < k0 + 32; ++k)
        s += p[k] * wcomb[k * D_OUT + o];
    part[ch][o] = s;
    __syncthreads();
    if (tid < D_OUT) {
        float t = bcomb[tid];
        for (int ch2 = 0; ch2 < 16; ++ch2) t += part[ch2][tid];
        out[g * D_OUT + tid] = t;
    }
}

// ---------------------------------------------------------------- launch

extern "C" void kernel_launch(void* const* d_in, const int* in_sizes, int n_in,
                              void* d_out, int out_size, void* d_ws, size_t ws_size,
                              hipStream_t stream) {
    const float* x     = (const float*)d_in[0];
    const int*   eidx  = (const int*)d_in[1];   // [2, E]
    const int*   batch = (const int*)d_in[2];
    const float* w1    = (const float*)d_in[3];
    const float* b1    = (const float*)d_in[4];
    const float* w2    = (const float*)d_in[5];
    const float* b2    = (const float*)d_in[6];
    const float* wc    = (const float*)d_in[7];
    const float* bc    = (const float*)d_in[8];
    float* out = (float*)d_out;
    const int* row = eidx;
    const int* col = eidx + N_EDGES;

    char* p = (char*)d_ws;
    auto alloc = [&](size_t bytes) { char* q = p; p += (bytes + 255) & ~(size_t)255; return q; };
    // zero-init region: bucket_cnt, gsum contiguous -> ONE memset
    char* zbase = p;
    int*   bucket_cnt = (int*)alloc((size_t)NBUK * 4);
    float* gsum       = (float*)alloc((size_t)N_GRAPHS * D_H * 4);
    size_t zbytes = (size_t)(p - zbase);
    int*   rowptr  = (int*)alloc((size_t)(N_NODES + 1) * 4);
    int*   gcnt    = (int*)alloc((size_t)N_GRAPHS * 4);
    float* invdeg  = (float*)alloc((size_t)N_NODES * 4);
    float* wcomb   = (float*)alloc((size_t)D_H * D_OUT * 4);
    float* bcomb   = (float*)alloc((size_t)D_OUT * 4);
    unsigned* edge_buf = (unsigned*)alloc((size_t)NBUK * BUK_CAP * 4);
    unsigned short* csr_col = (unsigned short*)alloc((size_t)N_EDGES * 2);
    unsigned short* xf  = (unsigned short*)alloc((size_t)N_NODES * 64 * 2);  // fp8x2
    unsigned short* h0f = (unsigned short*)alloc((size_t)N_NODES * 64 * 2);  // fp8x2
    unsigned short* h1f = (unsigned short*)alloc((size_t)N_NODES * 64 * 2);  // fp8x2
    unsigned* h3b  = (unsigned*)alloc((size_t)N_NODES * 64 * 4);             // bf16x2 node-major
    unsigned short* w1p = (unsigned short*)alloc((size_t)D_IN * D_H * 2);

    (void)hipMemsetAsync(zbase, 0, zbytes, stream);

    prep<<<12790, 256, 0, stream>>>(x, xf, w1, w1p, w2, wc, b2, bc, batch,
                                    wcomb, bcomb, gcnt);

    partition_edges<<<P1_BLOCKS, 512, 0, stream>>>(row, col, bucket_cnt, edge_buf);
    finalize_csr<<<NBUK, 512, 0, stream>>>(edge_buf, bucket_cnt, rowptr, invdeg, csr_col);

    int pgrid = (N_NODES + 1) / 2;
    propagate_fp8<<<pgrid, 128, 0, stream>>>(xf,  h0f, nullptr, 0, 8.0f,
                                             rowptr, csr_col, invdeg);
    propagate_fp8<<<pgrid, 128, 0, stream>>>(h0f, h1f, nullptr, 0, 8.0f,
                                             rowptr, csr_col, invdeg);
    propagate_fp8<<<pgrid, 128, 0, stream>>>(h1f, nullptr, h3b, 1, 1.0f / 64.0f,
                                             rowptr, csr_col, invdeg);

    dim3 ggrid((N_NODES + 63) / 64, D_H / 128);
    gemm_mfma_pool<<<ggrid, 256, 0, stream>>>((const unsigned short*)h3b, w1p, b1, batch, gsum);
    final_pool<<<N_GRAPHS, 256, 0, stream>>>(gsum, gcnt, wcomb, bcomb, out);
}

// Round 16
// 263.683 us; speedup vs baseline: 1.3589x; 1.0120x over previous
//
#include <hip/hip_runtime.h>
#include <hip/hip_bf16.h>
#include <hip/hip_fp8.h>

#define N_NODES 50000
#define N_EDGES 1600000
#define N_GRAPHS 64
#define D_IN 128
#define D_H 512
#define D_OUT 16

// atomic-free CSR build: buckets of 128 rows, 391 blocks for both phases
#define NBUK 391                      // ceil(50000/128)
#define BUK_CAP 4608                  // mean 4092 + ~8 sigma
#define P1_EDGES 4096                 // edges per partition block
#define P1_BLOCKS ((N_EDGES + P1_EDGES - 1) / P1_EDGES)   // 391

typedef short bf16x8 __attribute__((ext_vector_type(8)));
typedef float f32x4 __attribute__((ext_vector_type(4)));

static __device__ __forceinline__ unsigned short f2bf(float f) {
    __hip_bfloat16 h = __float2bfloat16(f);   // RNE
    return *(unsigned short*)&h;
}

static __device__ __forceinline__ float2 fp8x2_dec(unsigned short u) {
    __hip_fp8x2_e4m3 p;
    p.__x = (__hip_fp8x2_storage_t)u;
    return static_cast<float2>(p);
}

static __device__ __forceinline__ unsigned short fp8x2_enc(float a, float b) {
    __hip_fp8_e4m3 pa(a), pb(b);
    return (unsigned short)((unsigned)pa.__x | ((unsigned)pb.__x << 8));
}

// ---------------------------------------------------------------- CSR build (atomic-free)
// P1: 391 blocks x 512 threads, 4096 edges each. rec = (buk:9)<<23 | (rlow:7)<<16 | col:16.

__global__ __launch_bounds__(512) void partition_edges(const int* __restrict__ row,
                                                       const int* __restrict__ col,
                                                       int* __restrict__ bucket_cnt,
                                                       unsigned* __restrict__ edge_buf) {
    __shared__ unsigned recs[P1_EDGES];     // 16 KB
    __shared__ unsigned sorted[P1_EDGES];   // 16 KB
    __shared__ int hist4[4][NBUK];          // per-wave-pair counts -> local bases
    __shared__ int cur4[4][NBUK];
    __shared__ int gbase[NBUK];
    __shared__ int scan[512];
    int tid = threadIdx.x;
    int w2 = tid >> 7;                      // wave-pair 0..3
    int e0 = blockIdx.x * P1_EDGES;
    int m = N_EDGES - e0; if (m > P1_EDGES) m = P1_EDGES;

    for (int i = tid; i < 4 * NBUK; i += 512) ((int*)hist4)[i] = 0;
    for (int i = tid; i < 4 * NBUK; i += 512) ((int*)cur4)[i] = 0;
    __syncthreads();
    for (int i = tid; i < m; i += 512) {
        int r = row[e0 + i];
        int c = col[e0 + i];
        int buk = r >> 7;
        recs[i] = ((unsigned)buk << 23) | ((unsigned)(r & 127) << 16) | (unsigned)c;
        atomicAdd(&hist4[w2][buk], 1);
    }
    __syncthreads();
    int tot = 0;
    if (tid < NBUK) tot = hist4[0][tid] + hist4[1][tid] + hist4[2][tid] + hist4[3][tid];
    scan[tid] = (tid < NBUK) ? tot : 0;
    __syncthreads();
    for (int off = 1; off < 512; off <<= 1) {
        int v = (tid >= off) ? scan[tid - off] : 0;
        __syncthreads();
        scan[tid] += v;
        __syncthreads();
    }
    if (tid < NBUK) {
        int run = (tid == 0) ? 0 : scan[tid - 1];   // block-local excl base
        gbase[tid] = (tot > 0) ? atomicAdd(&bucket_cnt[tid], tot) : 0;  // reserve range
#pragma unroll
        for (int w = 0; w < 4; ++w) {               // per-sub-group local bases
            int c = hist4[w][tid];
            hist4[w][tid] = run;
            run += c;
        }
    }
    __syncthreads();
    for (int i = tid; i < m; i += 512) {            // rank + reorder (bucket-major)
        unsigned rec = recs[i];
        int buk = rec >> 23;
        int rank = atomicAdd(&cur4[w2][buk], 1);
        sorted[hist4[w2][buk] + rank] = rec;
    }
    __syncthreads();
    for (int p = tid; p < m; p += 512) {            // coalesced-run writes
        unsigned rec = sorted[p];
        int buk = rec >> 23;
        edge_buf[(size_t)buk * BUK_CAP + gbase[buk] + (p - hist4[0][buk])] = rec;
    }
}

// P2: one block per bucket (391 x 512); inline scan of bucket_cnt; LDS-cursor scatter.
__global__ __launch_bounds__(512) void finalize_csr(const unsigned* __restrict__ edge_buf,
                                                    const int* __restrict__ bucket_cnt,
                                                    int* __restrict__ rowptr,
                                                    float* __restrict__ invdeg,
                                                    unsigned short* __restrict__ csr_col) {
    __shared__ int hist[128], excl[128], cur[128];
    __shared__ int scan[512];
    int b = blockIdx.x;
    int tid = threadIdx.x;
    scan[tid] = (tid < NBUK) ? bucket_cnt[tid] : 0;
    __syncthreads();
    for (int off = 1; off < 512; off <<= 1) {
        int v = (tid >= off) ? scan[tid - off] : 0;
        __syncthreads();
        scan[tid] += v;
        __syncthreads();
    }
    int cnt = bucket_cnt[b];
    int base = (b == 0) ? 0 : scan[b - 1];
    const unsigned* src = edge_buf + (size_t)b * BUK_CAP;
    __syncthreads();
    if (tid < 128) { hist[tid] = 0; cur[tid] = 0; }
    __syncthreads();
    for (int i = tid; i < cnt; i += 512)
        atomicAdd(&hist[(src[i] >> 16) & 127], 1);
    __syncthreads();
    scan[tid] = (tid < 128) ? hist[tid] : 0;
    __syncthreads();
    for (int off = 1; off < 512; off <<= 1) {
        int v = (tid >= off) ? scan[tid - off] : 0;
        __syncthreads();
        scan[tid] += v;
        __syncthreads();
    }
    if (tid < 128) excl[tid] = (tid == 0) ? 0 : scan[tid - 1];
    __syncthreads();
    int r = b * 128 + tid;
    if (tid < 128 && r < N_NODES) {
        rowptr[r] = base + excl[tid];
        invdeg[r] = 1.0f / (float)(hist[tid] + 1);   // +1: self loop
    }
    if (b == NBUK - 1 && tid == 0) rowptr[N_NODES] = base + cnt;
    for (int i = tid; i < cnt; i += 512) {
        unsigned rec = src[i];
        int rl = (rec >> 16) & 127;
        int pos = excl[rl] + atomicAdd(&cur[rl], 1);
        csr_col[base + pos] = (unsigned short)(rec & 0xFFFFu);
    }
}

// ---------------------------------------------------------------- merged prep
// [0,12500): convert_x; [12500,12756): make_w1p; [12756,12790): fold_w + graph bounds.

__global__ __launch_bounds__(256) void prep(const float* __restrict__ x,
                                            unsigned short* __restrict__ xf,
                                            const float* __restrict__ w1,
                                            unsigned short* __restrict__ w1p,
                                            const float* __restrict__ w2,
                                            const float* __restrict__ wc,
                                            const float* __restrict__ b2,
                                            const float* __restrict__ bc,
                                            const int* __restrict__ batch,
                                            float* __restrict__ wcomb,
                                            float* __restrict__ bcomb,
                                            int* __restrict__ gcnt,
                                            int* __restrict__ gstart) {
    int b = blockIdx.x;
    int tid = threadIdx.x;
    if (b < 12500) {                                // convert_x: 12500*256 == N*64 exactly
        int i = b * 256 + tid;
        float2 v = ((const float2*)x)[i];
        xf[i] = fp8x2_enc(v.x, v.y);
        return;
    }
    if (b < 12756) {                                // make_w1p: 256 blocks, 65536 elems
        int i = (b - 12500) * 256 + tid;
        int j = i & 7, lane = (i >> 3) & 63, s = (i >> 9) & 3, t = i >> 11;
        int k = s * 32 + (lane >> 4) * 8 + j;
        int n = t * 16 + (lane & 15);
        w1p[i] = f2bf(w1[(size_t)k * D_H + n]);
        return;
    }
    int fb = b - 12756;                             // fold_w blocks 0..33
    if (fb == 33) {
        if (tid < N_GRAPHS) {
            int g = tid;
            int lo = 0, hi = N_NODES;
            while (lo < hi) { int mid = (lo + hi) >> 1; if (batch[mid] < g) lo = mid + 1; else hi = mid; }
            int a = lo;
            lo = 0; hi = N_NODES;
            while (lo < hi) { int mid = (lo + hi) >> 1; if (batch[mid] < g + 1) lo = mid + 1; else hi = mid; }
            gcnt[g] = lo - a;
            gstart[g] = a;
            if (g == N_GRAPHS - 1) gstart[N_GRAPHS] = N_NODES;
        }
        return;
    }
    int o = tid & 15, kl = tid >> 4;
    int k = fb * 16 + kl;
    if (k > D_H) return;
    const float* wr = (k < D_H) ? (w2 + (size_t)k * D_H) : b2;
    float s = 0.f;
    for (int j = 0; j < D_H; j += 4) {
        s += wr[j + 0] * wc[(j + 0) * D_OUT + o]
           + wr[j + 1] * wc[(j + 1) * D_OUT + o]
           + wr[j + 2] * wc[(j + 2) * D_OUT + o]
           + wr[j + 3] * wc[(j + 3) * D_OUT + o];
    }
    if (k < D_H) wcomb[k * D_OUT + o] = s;
    else         bcomb[o] = s + bc[o];
}

// ---------------------------------------------------------------- propagation (fp8 storage, f32 accumulate)

__global__ __launch_bounds__(128) void propagate_fp8(const unsigned short* __restrict__ xin,
                                                     unsigned short* __restrict__ out8,
                                                     unsigned* __restrict__ out16,
                                                     int last, float extra,
                                                     const int* __restrict__ rowptr,
                                                     const unsigned short* __restrict__ csr_col,
                                                     const float* __restrict__ invdeg) {
    int wave = threadIdx.x >> 6;
    int lane = threadIdx.x & 63;
    int r = blockIdx.x * 2 + wave;
    if (r >= N_NODES) return;
    int beg = rowptr[r], end = rowptr[r + 1];
    float2 sv = fp8x2_dec(xin[(size_t)r * 64 + lane]);   // self loop
    float acc0 = sv.x, acc1 = sv.y;
    for (int cs = beg; cs < end; cs += 64) {
        int nn = end - cs; if (nn > 64) nn = 64;
        int colv = (int)csr_col[cs + (lane < nn ? lane : 0)];
        int j = 0;
        for (; j + 16 <= nn; j += 16) {           // 16 independent 128B gathers in flight
            unsigned short uu[16];
#pragma unroll
            for (int q = 0; q < 16; ++q) {
                int c = __shfl(colv, j + q, 64);
                uu[q] = xin[(size_t)c * 64 + lane];
            }
#pragma unroll
            for (int q = 0; q < 16; ++q) {
                float2 v = fp8x2_dec(uu[q]);
                acc0 += v.x; acc1 += v.y;
            }
        }
        for (; j + 4 <= nn; j += 4) {
            unsigned short u0, u1, u2, u3;
            {
                int c0 = __shfl(colv, j + 0, 64), c1 = __shfl(colv, j + 1, 64);
                int c2 = __shfl(colv, j + 2, 64), c3 = __shfl(colv, j + 3, 64);
                u0 = xin[(size_t)c0 * 64 + lane];
                u1 = xin[(size_t)c1 * 64 + lane];
                u2 = xin[(size_t)c2 * 64 + lane];
                u3 = xin[(size_t)c3 * 64 + lane];
            }
            float2 v0 = fp8x2_dec(u0), v1 = fp8x2_dec(u1);
            float2 v2 = fp8x2_dec(u2), v3 = fp8x2_dec(u3);
            acc0 += v0.x + v1.x + v2.x + v3.x;
            acc1 += v0.y + v1.y + v2.y + v3.y;
        }
        for (; j < nn; ++j) {
            int c = __shfl(colv, j, 64);
            float2 v = fp8x2_dec(xin[(size_t)c * 64 + lane]);
            acc0 += v.x; acc1 += v.y;
        }
    }
    float s = invdeg[r] * extra;
    acc0 *= s; acc1 *= s;
    if (last) {
        out16[(size_t)r * 64 + lane] = (unsigned)f2bf(acc0) | ((unsigned)f2bf(acc1) << 16);
    } else {
        out8[(size_t)r * 64 + lane] = fp8x2_enc(acc0, acc1);
    }
}

// ---------------------------------------------------------------- MFMA GEMM + pool, graph-aligned (ZERO atomics)
// grid (64 graphs, 4 col-groups); block owns rows gstart[g]..gstart[g+1] and 128 cols.
// B-fragments hoisted to registers (reused across ~13 M-tiles); per-thread register
// accumulation of the bias+ReLU segment sum; single plain store per (g,c).

__global__ __launch_bounds__(256) void gemm_graph_pool(const unsigned short* __restrict__ h3b,
                                                       const unsigned short* __restrict__ w1p,
                                                       const float* __restrict__ b1,
                                                       const int* __restrict__ gstart,
                                                       float* __restrict__ gsum) {
    __shared__ float hls[64][132];   // +4 pad: conflict-free row-strided writes
    __shared__ float sum2[2][128];
    int tid = threadIdx.x;
    int lane = tid & 63, wave = tid >> 6;
    int quad = lane >> 4, l15 = lane & 15;
    int g = blockIdx.x;
    int nbase = blockIdx.y * 128;
    int r0 = gstart[g], r1 = gstart[g + 1];

    bf16x8 bfr[32];                  // 128 VGPRs: whole B tile for this col-group
    const unsigned short* bbase = w1p + ((size_t)(blockIdx.y * 8) * 4 * 64 + lane) * 8;
#pragma unroll
    for (int i = 0; i < 32; ++i)
        bfr[i] = *(const bf16x8*)(bbase + (size_t)i * 64 * 8);

    int c = tid & 127, half = tid >> 7;
    float bias = b1[nbase + c];
    float gacc = 0.f;

    for (int mbase = r0; mbase < r1; mbase += 64) {
        int m = mbase + wave * 16 + l15;
        int mc = m < N_NODES ? m : N_NODES - 1;      // clamp; out-of-graph rows skipped below
        const unsigned short* arow = h3b + (size_t)mc * 128 + quad * 8;
        bf16x8 afrag[4];
#pragma unroll
        for (int s = 0; s < 4; ++s)
            afrag[s] = *(const bf16x8*)(arow + s * 32);

        f32x4 acc[8];
#pragma unroll
        for (int t = 0; t < 8; ++t) acc[t] = (f32x4){0.f, 0.f, 0.f, 0.f};
#pragma unroll
        for (int t = 0; t < 8; ++t)
#pragma unroll
            for (int s = 0; s < 4; ++s)
                acc[t] = __builtin_amdgcn_mfma_f32_16x16x32_bf16(afrag[s], bfr[t * 4 + s],
                                                                 acc[t], 0, 0, 0);
        __syncthreads();             // previous tile's epilogue reads done
#pragma unroll
        for (int t = 0; t < 8; ++t)
#pragma unroll
            for (int rg = 0; rg < 4; ++rg)
                hls[wave * 16 + quad * 4 + rg][t * 16 + l15] = acc[t][rg];
        __syncthreads();

        int rend = r1 - mbase; if (rend > 64) rend = 64;
        int rs = half * 32;
        int re = rs + 32 < rend ? rs + 32 : rend;
        for (int r = rs; r < re; ++r) {
            float v = hls[r][c] + bias;
            gacc += v > 0.f ? v : 0.f;
        }
    }
    sum2[half][c] = gacc;
    __syncthreads();
    if (half == 0)
        gsum[g * D_H + nbase + c] = sum2[0][c] + sum2[1][c];
}

// ---------------------------------------------------------------- final: mean + folded (512x16) projection

__global__ __launch_bounds__(256) void final_pool(const float* __restrict__ gsum,
                                                  const int* __restrict__ gcnt,
                                                  const float* __restrict__ wcomb,
                                                  const float* __restrict__ bcomb,
                                                  float* __restrict__ out) {
    int g = blockIdx.x;
    int tid = threadIdx.x;
    __shared__ float p[D_H];
    __shared__ float part[16][17];
    int c = gcnt[g]; if (c < 1) c = 1;
    float inv = 1.0f / (float)c;
    p[tid] = gsum[g * D_H + tid] * inv;
    p[tid + 256] = gsum[g * D_H + tid + 256] * inv;
    __syncthreads();
    int o = tid & 15, ch = tid >> 4;
    int k0 = ch * 32;
    float s = 0.f;
    for (int k = k0; k < k0 + 32; ++k)
        s += p[k] * wcomb[k * D_OUT + o];
    part[ch][o] = s;
    __syncthreads();
    if (tid < D_OUT) {
        float t = bcomb[tid];
        for (int ch2 = 0; ch2 < 16; ++ch2) t += part[ch2][tid];
        out[g * D_OUT + tid] = t;
    }
}

// ---------------------------------------------------------------- launch

extern "C" void kernel_launch(void* const* d_in, const int* in_sizes, int n_in,
                              void* d_out, int out_size, void* d_ws, size_t ws_size,
                              hipStream_t stream) {
    const float* x     = (const float*)d_in[0];
    const int*   eidx  = (const int*)d_in[1];   // [2, E]
    const int*   batch = (const int*)d_in[2];
    const float* w1    = (const float*)d_in[3];
    const float* b1    = (const float*)d_in[4];
    const float* w2    = (const float*)d_in[5];
    const float* b2    = (const float*)d_in[6];
    const float* wc    = (const float*)d_in[7];
    const float* bc    = (const float*)d_in[8];
    float* out = (float*)d_out;
    const int* row = eidx;
    const int* col = eidx + N_EDGES;

    char* p = (char*)d_ws;
    auto alloc = [&](size_t bytes) { char* q = p; p += (bytes + 255) & ~(size_t)255; return q; };
    // zero-init region: only bucket_cnt (gsum now fully overwritten, no memset needed)
    char* zbase = p;
    int*   bucket_cnt = (int*)alloc((size_t)NBUK * 4);
    size_t zbytes = (size_t)(p - zbase);
    float* gsum    = (float*)alloc((size_t)N_GRAPHS * D_H * 4);
    int*   rowptr  = (int*)alloc((size_t)(N_NODES + 1) * 4);
    int*   gcnt    = (int*)alloc((size_t)N_GRAPHS * 4);
    int*   gstart  = (int*)alloc((size_t)(N_GRAPHS + 1) * 4);
    float* invdeg  = (float*)alloc((size_t)N_NODES * 4);
    float* wcomb   = (float*)alloc((size_t)D_H * D_OUT * 4);
    float* bcomb   = (float*)alloc((size_t)D_OUT * 4);
    unsigned* edge_buf = (unsigned*)alloc((size_t)NBUK * BUK_CAP * 4);
    unsigned short* csr_col = (unsigned short*)alloc((size_t)N_EDGES * 2);
    unsigned short* xf  = (unsigned short*)alloc((size_t)N_NODES * 64 * 2);  // fp8x2
    unsigned short* h0f = (unsigned short*)alloc((size_t)N_NODES * 64 * 2);  // fp8x2
    unsigned short* h1f = (unsigned short*)alloc((size_t)N_NODES * 64 * 2);  // fp8x2
    unsigned* h3b  = (unsigned*)alloc((size_t)N_NODES * 64 * 4);             // bf16x2 node-major
    unsigned short* w1p = (unsigned short*)alloc((size_t)D_IN * D_H * 2);

    (void)hipMemsetAsync(zbase, 0, zbytes, stream);

    prep<<<12790, 256, 0, stream>>>(x, xf, w1, w1p, w2, wc, b2, bc, batch,
                                    wcomb, bcomb, gcnt, gstart);

    partition_edges<<<P1_BLOCKS, 512, 0, stream>>>(row, col, bucket_cnt, edge_buf);
    finalize_csr<<<NBUK, 512, 0, stream>>>(edge_buf, bucket_cnt, rowptr, invdeg, csr_col);

    int pgrid = (N_NODES + 1) / 2;
    propagate_fp8<<<pgrid, 128, 0, stream>>>(xf,  h0f, nullptr, 0, 8.0f,
                                             rowptr, csr_col, invdeg);
    propagate_fp8<<<pgrid, 128, 0, stream>>>(h0f, h1f, nullptr, 0, 8.0f,
                                             rowptr, csr_col, invdeg);
    propagate_fp8<<<pgrid, 128, 0, stream>>>(h1f, nullptr, h3b, 1, 1.0f / 64.0f,
                                             rowptr, csr_col, invdeg);

    dim3 ggrid(N_GRAPHS, D_H / 128);
    gemm_graph_pool<<<ggrid, 256, 0, stream>>>((const unsigned short*)h3b, w1p, b1,
                                               gstart, gsum);
    final_pool<<<N_GRAPHS, 256, 0, stream>>>(gsum, gcnt, wcomb, bcomb, out);
}

// Round 17
// 252.217 us; speedup vs baseline: 1.4207x; 1.0455x over previous
//
#include <hip/hip_runtime.h>
#include <hip/hip_bf16.h>
#include <hip/hip_fp8.h>

#define N_NODES 50000
#define N_EDGES 1600000
#define N_GRAPHS 64
#define D_IN 128
#define D_H 512
#define D_OUT 16

// atomic-free CSR build: buckets of 128 rows, 391 blocks for both phases
#define NBUK 391                      // ceil(50000/128)
#define BUK_CAP 4608                  // mean 4092 + ~8 sigma
#define P1_EDGES 4096                 // edges per partition block
#define P1_BLOCKS ((N_EDGES + P1_EDGES - 1) / P1_EDGES)   // 391

#define MSPLIT 4                      // M-tile interleave factor for the GEMM

typedef short bf16x8 __attribute__((ext_vector_type(8)));
typedef float f32x4 __attribute__((ext_vector_type(4)));

static __device__ __forceinline__ unsigned short f2bf(float f) {
    __hip_bfloat16 h = __float2bfloat16(f);   // RNE
    return *(unsigned short*)&h;
}

static __device__ __forceinline__ float2 fp8x2_dec(unsigned short u) {
    __hip_fp8x2_e4m3 p;
    p.__x = (__hip_fp8x2_storage_t)u;
    return static_cast<float2>(p);
}

static __device__ __forceinline__ unsigned short fp8x2_enc(float a, float b) {
    __hip_fp8_e4m3 pa(a), pb(b);
    return (unsigned short)((unsigned)pa.__x | ((unsigned)pb.__x << 8));
}

// ---------------------------------------------------------------- CSR build (atomic-free)
// P1: 391 blocks x 512 threads, 4096 edges each. rec = (buk:9)<<23 | (rlow:7)<<16 | col:16.

__global__ __launch_bounds__(512) void partition_edges(const int* __restrict__ row,
                                                       const int* __restrict__ col,
                                                       int* __restrict__ bucket_cnt,
                                                       unsigned* __restrict__ edge_buf) {
    __shared__ unsigned recs[P1_EDGES];     // 16 KB
    __shared__ unsigned sorted[P1_EDGES];   // 16 KB
    __shared__ int hist4[4][NBUK];          // per-wave-pair counts -> local bases
    __shared__ int cur4[4][NBUK];
    __shared__ int gbase[NBUK];
    __shared__ int scan[512];
    int tid = threadIdx.x;
    int w2 = tid >> 7;                      // wave-pair 0..3
    int e0 = blockIdx.x * P1_EDGES;
    int m = N_EDGES - e0; if (m > P1_EDGES) m = P1_EDGES;

    for (int i = tid; i < 4 * NBUK; i += 512) ((int*)hist4)[i] = 0;
    for (int i = tid; i < 4 * NBUK; i += 512) ((int*)cur4)[i] = 0;
    __syncthreads();
    for (int i = tid; i < m; i += 512) {
        int r = row[e0 + i];
        int c = col[e0 + i];
        int buk = r >> 7;
        recs[i] = ((unsigned)buk << 23) | ((unsigned)(r & 127) << 16) | (unsigned)c;
        atomicAdd(&hist4[w2][buk], 1);
    }
    __syncthreads();
    int tot = 0;
    if (tid < NBUK) tot = hist4[0][tid] + hist4[1][tid] + hist4[2][tid] + hist4[3][tid];
    scan[tid] = (tid < NBUK) ? tot : 0;
    __syncthreads();
    for (int off = 1; off < 512; off <<= 1) {
        int v = (tid >= off) ? scan[tid - off] : 0;
        __syncthreads();
        scan[tid] += v;
        __syncthreads();
    }
    if (tid < NBUK) {
        int run = (tid == 0) ? 0 : scan[tid - 1];   // block-local excl base
        gbase[tid] = (tot > 0) ? atomicAdd(&bucket_cnt[tid], tot) : 0;  // reserve range
#pragma unroll
        for (int w = 0; w < 4; ++w) {               // per-sub-group local bases
            int c = hist4[w][tid];
            hist4[w][tid] = run;
            run += c;
        }
    }
    __syncthreads();
    for (int i = tid; i < m; i += 512) {            // rank + reorder (bucket-major)
        unsigned rec = recs[i];
        int buk = rec >> 23;
        int rank = atomicAdd(&cur4[w2][buk], 1);
        sorted[hist4[w2][buk] + rank] = rec;
    }
    __syncthreads();
    for (int p = tid; p < m; p += 512) {            // coalesced-run writes
        unsigned rec = sorted[p];
        int buk = rec >> 23;
        edge_buf[(size_t)buk * BUK_CAP + gbase[buk] + (p - hist4[0][buk])] = rec;
    }
}

// P2: one block per bucket (391 x 512); inline scan of bucket_cnt; LDS-cursor scatter.
__global__ __launch_bounds__(512) void finalize_csr(const unsigned* __restrict__ edge_buf,
                                                    const int* __restrict__ bucket_cnt,
                                                    int* __restrict__ rowptr,
                                                    float* __restrict__ invdeg,
                                                    unsigned short* __restrict__ csr_col) {
    __shared__ int hist[128], excl[128], cur[128];
    __shared__ int scan[512];
    int b = blockIdx.x;
    int tid = threadIdx.x;
    scan[tid] = (tid < NBUK) ? bucket_cnt[tid] : 0;
    __syncthreads();
    for (int off = 1; off < 512; off <<= 1) {
        int v = (tid >= off) ? scan[tid - off] : 0;
        __syncthreads();
        scan[tid] += v;
        __syncthreads();
    }
    int cnt = bucket_cnt[b];
    int base = (b == 0) ? 0 : scan[b - 1];
    const unsigned* src = edge_buf + (size_t)b * BUK_CAP;
    __syncthreads();
    if (tid < 128) { hist[tid] = 0; cur[tid] = 0; }
    __syncthreads();
    for (int i = tid; i < cnt; i += 512)
        atomicAdd(&hist[(src[i] >> 16) & 127], 1);
    __syncthreads();
    scan[tid] = (tid < 128) ? hist[tid] : 0;
    __syncthreads();
    for (int off = 1; off < 512; off <<= 1) {
        int v = (tid >= off) ? scan[tid - off] : 0;
        __syncthreads();
        scan[tid] += v;
        __syncthreads();
    }
    if (tid < 128) excl[tid] = (tid == 0) ? 0 : scan[tid - 1];
    __syncthreads();
    int r = b * 128 + tid;
    if (tid < 128 && r < N_NODES) {
        rowptr[r] = base + excl[tid];
        invdeg[r] = 1.0f / (float)(hist[tid] + 1);   // +1: self loop
    }
    if (b == NBUK - 1 && tid == 0) rowptr[N_NODES] = base + cnt;
    for (int i = tid; i < cnt; i += 512) {
        unsigned rec = src[i];
        int rl = (rec >> 16) & 127;
        int pos = excl[rl] + atomicAdd(&cur[rl], 1);
        csr_col[base + pos] = (unsigned short)(rec & 0xFFFFu);
    }
}

// ---------------------------------------------------------------- merged prep
// [0,12500): convert_x; [12500,12756): make_w1p; [12756,12790): fold_w + graph bounds.

__global__ __launch_bounds__(256) void prep(const float* __restrict__ x,
                                            unsigned short* __restrict__ xf,
                                            const float* __restrict__ w1,
                                            unsigned short* __restrict__ w1p,
                                            const float* __restrict__ w2,
                                            const float* __restrict__ wc,
                                            const float* __restrict__ b2,
                                            const float* __restrict__ bc,
                                            const int* __restrict__ batch,
                                            float* __restrict__ wcomb,
                                            float* __restrict__ bcomb,
                                            int* __restrict__ gcnt,
                                            int* __restrict__ gstart) {
    int b = blockIdx.x;
    int tid = threadIdx.x;
    if (b < 12500) {                                // convert_x: 12500*256 == N*64 exactly
        int i = b * 256 + tid;
        float2 v = ((const float2*)x)[i];
        xf[i] = fp8x2_enc(v.x, v.y);
        return;
    }
    if (b < 12756) {                                // make_w1p: 256 blocks, 65536 elems
        int i = (b - 12500) * 256 + tid;
        int j = i & 7, lane = (i >> 3) & 63, s = (i >> 9) & 3, t = i >> 11;
        int k = s * 32 + (lane >> 4) * 8 + j;
        int n = t * 16 + (lane & 15);
        w1p[i] = f2bf(w1[(size_t)k * D_H + n]);
        return;
    }
    int fb = b - 12756;                             // fold_w blocks 0..33
    if (fb == 33) {
        if (tid < N_GRAPHS) {
            int g = tid;
            int lo = 0, hi = N_NODES;
            while (lo < hi) { int mid = (lo + hi) >> 1; if (batch[mid] < g) lo = mid + 1; else hi = mid; }
            int a = lo;
            lo = 0; hi = N_NODES;
            while (lo < hi) { int mid = (lo + hi) >> 1; if (batch[mid] < g + 1) lo = mid + 1; else hi = mid; }
            gcnt[g] = lo - a;
            gstart[g] = a;
            if (g == N_GRAPHS - 1) gstart[N_GRAPHS] = N_NODES;
        }
        return;
    }
    int o = tid & 15, kl = tid >> 4;
    int k = fb * 16 + kl;
    if (k > D_H) return;
    const float* wr = (k < D_H) ? (w2 + (size_t)k * D_H) : b2;
    float s = 0.f;
    for (int j = 0; j < D_H; j += 4) {
        s += wr[j + 0] * wc[(j + 0) * D_OUT + o]
           + wr[j + 1] * wc[(j + 1) * D_OUT + o]
           + wr[j + 2] * wc[(j + 2) * D_OUT + o]
           + wr[j + 3] * wc[(j + 3) * D_OUT + o];
    }
    if (k < D_H) wcomb[k * D_OUT + o] = s;
    else         bcomb[o] = s + bc[o];
}

// ---------------------------------------------------------------- propagation (fp8 storage, f32 accumulate)
// Frozen shape (12 rounds of probes): one row per wave, full-wave contiguous 128B
// row gather, shfl-broadcast indices, 16 gathers in flight.

__global__ __launch_bounds__(128) void propagate_fp8(const unsigned short* __restrict__ xin,
                                                     unsigned short* __restrict__ out8,
                                                     unsigned* __restrict__ out16,
                                                     int last, float extra,
                                                     const int* __restrict__ rowptr,
                                                     const unsigned short* __restrict__ csr_col,
                                                     const float* __restrict__ invdeg) {
    int wave = threadIdx.x >> 6;
    int lane = threadIdx.x & 63;
    int r = blockIdx.x * 2 + wave;
    if (r >= N_NODES) return;
    int beg = rowptr[r], end = rowptr[r + 1];
    float2 sv = fp8x2_dec(xin[(size_t)r * 64 + lane]);   // self loop
    float acc0 = sv.x, acc1 = sv.y;
    for (int cs = beg; cs < end; cs += 64) {
        int nn = end - cs; if (nn > 64) nn = 64;
        int colv = (int)csr_col[cs + (lane < nn ? lane : 0)];
        int j = 0;
        for (; j + 16 <= nn; j += 16) {           // 16 independent 128B gathers in flight
            unsigned short uu[16];
#pragma unroll
            for (int q = 0; q < 16; ++q) {
                int c = __shfl(colv, j + q, 64);
                uu[q] = xin[(size_t)c * 64 + lane];
            }
#pragma unroll
            for (int q = 0; q < 16; ++q) {
                float2 v = fp8x2_dec(uu[q]);
                acc0 += v.x; acc1 += v.y;
            }
        }
        for (; j + 4 <= nn; j += 4) {
            unsigned short u0, u1, u2, u3;
            {
                int c0 = __shfl(colv, j + 0, 64), c1 = __shfl(colv, j + 1, 64);
                int c2 = __shfl(colv, j + 2, 64), c3 = __shfl(colv, j + 3, 64);
                u0 = xin[(size_t)c0 * 64 + lane];
                u1 = xin[(size_t)c1 * 64 + lane];
                u2 = xin[(size_t)c2 * 64 + lane];
                u3 = xin[(size_t)c3 * 64 + lane];
            }
            float2 v0 = fp8x2_dec(u0), v1 = fp8x2_dec(u1);
            float2 v2 = fp8x2_dec(u2), v3 = fp8x2_dec(u3);
            acc0 += v0.x + v1.x + v2.x + v3.x;
            acc1 += v0.y + v1.y + v2.y + v3.y;
        }
        for (; j < nn; ++j) {
            int c = __shfl(colv, j, 64);
            float2 v = fp8x2_dec(xin[(size_t)c * 64 + lane]);
            acc0 += v.x; acc1 += v.y;
        }
    }
    float s = invdeg[r] * extra;
    acc0 *= s; acc1 *= s;
    if (last) {
        out16[(size_t)r * 64 + lane] = (unsigned)f2bf(acc0) | ((unsigned)f2bf(acc1) << 16);
    } else {
        out8[(size_t)r * 64 + lane] = fp8x2_enc(acc0, acc1);
    }
}

// ---------------------------------------------------------------- MFMA GEMM + pool, graph-aligned, zero atomics
// grid (64 graphs, 4 col-groups, MSPLIT m-interleave) = 1024 blocks (4/CU, 16 waves/CU).
// Block handles tiles mbase = r0 + 64*(ms + MSPLIT*k); partials to disjoint gsum slabs.

__global__ __launch_bounds__(256) void gemm_graph_pool(const unsigned short* __restrict__ h3b,
                                                       const unsigned short* __restrict__ w1p,
                                                       const float* __restrict__ b1,
                                                       const int* __restrict__ gstart,
                                                       float* __restrict__ gsum) {
    __shared__ float hls[64][132];   // +4 pad: conflict-free row-strided writes
    __shared__ float sum2[2][128];
    int tid = threadIdx.x;
    int lane = tid & 63, wave = tid >> 6;
    int quad = lane >> 4, l15 = lane & 15;
    int g = blockIdx.x;
    int nbase = blockIdx.y * 128;
    int ms = blockIdx.z;
    int r0 = gstart[g], r1 = gstart[g + 1];

    bf16x8 bfr[32];                  // whole B tile for this col-group in registers
    const unsigned short* bbase = w1p + ((size_t)(blockIdx.y * 8) * 4 * 64 + lane) * 8;
#pragma unroll
    for (int i = 0; i < 32; ++i)
        bfr[i] = *(const bf16x8*)(bbase + (size_t)i * 64 * 8);

    int c = tid & 127, half = tid >> 7;
    float bias = b1[nbase + c];
    float gacc = 0.f;

    for (int mbase = r0 + ms * 64; mbase < r1; mbase += 64 * MSPLIT) {
        int m = mbase + wave * 16 + l15;
        int mc = m < N_NODES ? m : N_NODES - 1;      // clamp; out-of-graph rows skipped below
        const unsigned short* arow = h3b + (size_t)mc * 128 + quad * 8;
        bf16x8 afrag[4];
#pragma unroll
        for (int s = 0; s < 4; ++s)
            afrag[s] = *(const bf16x8*)(arow + s * 32);

        f32x4 acc[8];
#pragma unroll
        for (int t = 0; t < 8; ++t) acc[t] = (f32x4){0.f, 0.f, 0.f, 0.f};
#pragma unroll
        for (int t = 0; t < 8; ++t)
#pragma unroll
            for (int s = 0; s < 4; ++s)
                acc[t] = __builtin_amdgcn_mfma_f32_16x16x32_bf16(afrag[s], bfr[t * 4 + s],
                                                                 acc[t], 0, 0, 0);
        __syncthreads();             // previous tile's epilogue reads done
#pragma unroll
        for (int t = 0; t < 8; ++t)
#pragma unroll
            for (int rg = 0; rg < 4; ++rg)
                hls[wave * 16 + quad * 4 + rg][t * 16 + l15] = acc[t][rg];
        __syncthreads();

        int rend = r1 - mbase; if (rend > 64) rend = 64;
        int rs = half * 32;
        int re = rs + 32 < rend ? rs + 32 : rend;
        for (int r = rs; r < re; ++r) {
            float v = hls[r][c] + bias;
            gacc += v > 0.f ? v : 0.f;
        }
    }
    sum2[half][c] = gacc;
    __syncthreads();
    if (half == 0)
        gsum[((size_t)ms * N_GRAPHS + g) * D_H + nbase + c] = sum2[0][c] + sum2[1][c];
}

// ---------------------------------------------------------------- final: mean + folded (512x16) projection

__global__ __launch_bounds__(256) void final_pool(const float* __restrict__ gsum,
                                                  const int* __restrict__ gcnt,
                                                  const float* __restrict__ wcomb,
                                                  const float* __restrict__ bcomb,
                                                  float* __restrict__ out) {
    int g = blockIdx.x;
    int tid = threadIdx.x;
    __shared__ float p[D_H];
    __shared__ float part[16][17];
    int c = gcnt[g]; if (c < 1) c = 1;
    float inv = 1.0f / (float)c;
#pragma unroll
    for (int h = 0; h < 2; ++h) {
        int i = tid + h * 256;
        float v = 0.f;
#pragma unroll
        for (int ms = 0; ms < MSPLIT; ++ms)
            v += gsum[((size_t)ms * N_GRAPHS + g) * D_H + i];
        p[i] = v * inv;
    }
    __syncthreads();
    int o = tid & 15, ch = tid >> 4;
    int k0 = ch * 32;
    float s = 0.f;
    for (int k = k0; k < k0 + 32; ++k)
        s += p[k] * wcomb[k * D_OUT + o];
    part[ch][o] = s;
    __syncthreads();
    if (tid < D_OUT) {
        float t = bcomb[tid];
        for (int ch2 = 0; ch2 < 16; ++ch2) t += part[ch2][tid];
        out[g * D_OUT + tid] = t;
    }
}

// ---------------------------------------------------------------- launch

extern "C" void kernel_launch(void* const* d_in, const int* in_sizes, int n_in,
                              void* d_out, int out_size, void* d_ws, size_t ws_size,
                              hipStream_t stream) {
    const float* x     = (const float*)d_in[0];
    const int*   eidx  = (const int*)d_in[1];   // [2, E]
    const int*   batch = (const int*)d_in[2];
    const float* w1    = (const float*)d_in[3];
    const float* b1    = (const float*)d_in[4];
    const float* w2    = (const float*)d_in[5];
    const float* b2    = (const float*)d_in[6];
    const float* wc    = (const float*)d_in[7];
    const float* bc    = (const float*)d_in[8];
    float* out = (float*)d_out;
    const int* row = eidx;
    const int* col = eidx + N_EDGES;

    char* p = (char*)d_ws;
    auto alloc = [&](size_t bytes) { char* q = p; p += (bytes + 255) & ~(size_t)255; return q; };
    // zero-init region: only bucket_cnt
    char* zbase = p;
    int*   bucket_cnt = (int*)alloc((size_t)NBUK * 4);
    size_t zbytes = (size_t)(p - zbase);
    float* gsum    = (float*)alloc((size_t)MSPLIT * N_GRAPHS * D_H * 4);
    int*   rowptr  = (int*)alloc((size_t)(N_NODES + 1) * 4);
    int*   gcnt    = (int*)alloc((size_t)N_GRAPHS * 4);
    int*   gstart  = (int*)alloc((size_t)(N_GRAPHS + 1) * 4);
    float* invdeg  = (float*)alloc((size_t)N_NODES * 4);
    float* wcomb   = (float*)alloc((size_t)D_H * D_OUT * 4);
    float* bcomb   = (float*)alloc((size_t)D_OUT * 4);
    unsigned* edge_buf = (unsigned*)alloc((size_t)NBUK * BUK_CAP * 4);
    unsigned short* csr_col = (unsigned short*)alloc((size_t)N_EDGES * 2);
    unsigned short* xf  = (unsigned short*)alloc((size_t)N_NODES * 64 * 2);  // fp8x2
    unsigned short* h0f = (unsigned short*)alloc((size_t)N_NODES * 64 * 2);  // fp8x2
    unsigned short* h1f = (unsigned short*)alloc((size_t)N_NODES * 64 * 2);  // fp8x2
    unsigned* h3b  = (unsigned*)alloc((size_t)N_NODES * 64 * 4);             // bf16x2 node-major
    unsigned short* w1p = (unsigned short*)alloc((size_t)D_IN * D_H * 2);

    (void)hipMemsetAsync(zbase, 0, zbytes, stream);

    prep<<<12790, 256, 0, stream>>>(x, xf, w1, w1p, w2, wc, b2, bc, batch,
                                    wcomb, bcomb, gcnt, gstart);

    partition_edges<<<P1_BLOCKS, 512, 0, stream>>>(row, col, bucket_cnt, edge_buf);
    finalize_csr<<<NBUK, 512, 0, stream>>>(edge_buf, bucket_cnt, rowptr, invdeg, csr_col);

    int pgrid = (N_NODES + 1) / 2;
    propagate_fp8<<<pgrid, 128, 0, stream>>>(xf,  h0f, nullptr, 0, 8.0f,
                                             rowptr, csr_col, invdeg);
    propagate_fp8<<<pgrid, 128, 0, stream>>>(h0f, h1f, nullptr, 0, 8.0f,
                                             rowptr, csr_col, invdeg);
    propagate_fp8<<<pgrid, 128, 0, stream>>>(h1f, nullptr, h3b, 1, 1.0f / 64.0f,
                                             rowptr, csr_col, invdeg);

    dim3 ggrid(N_GRAPHS, D_H / 128, MSPLIT);
    gemm_graph_pool<<<ggrid, 256, 0, stream>>>((const unsigned short*)h3b, w1p, b1,
                                               gstart, gsum);
    final_pool<<<N_GRAPHS, 256, 0, stream>>>(gsum, gcnt, wcomb, bcomb, out);
}

// Round 18
// 249.294 us; speedup vs baseline: 1.4374x; 1.0117x over previous
//
#include <hip/hip_runtime.h>
#include <hip/hip_bf16.h>
#include <hip/hip_fp8.h>

#define N_NODES 50000
#define N_EDGES 1600000
#define N_GRAPHS 64
#define D_IN 128
#define D_H 512
#define D_OUT 16

// atomic-free CSR build: buckets of 128 rows, 391 blocks for both phases
#define NBUK 391                      // ceil(50000/128)
#define BUK_CAP 4608                  // mean 4092 + ~8 sigma
#define P1_EDGES 4096                 // edges per partition block
#define P1_BLOCKS ((N_EDGES + P1_EDGES - 1) / P1_EDGES)   // 391

#define MSPLIT 8                      // M-tile interleave factor for the GEMM

typedef short bf16x8 __attribute__((ext_vector_type(8)));
typedef float f32x4 __attribute__((ext_vector_type(4)));

static __device__ __forceinline__ unsigned short f2bf(float f) {
    __hip_bfloat16 h = __float2bfloat16(f);   // RNE
    return *(unsigned short*)&h;
}

static __device__ __forceinline__ float2 fp8x2_dec(unsigned short u) {
    __hip_fp8x2_e4m3 p;
    p.__x = (__hip_fp8x2_storage_t)u;
    return static_cast<float2>(p);
}

static __device__ __forceinline__ unsigned short fp8x2_enc(float a, float b) {
    __hip_fp8_e4m3 pa(a), pb(b);
    return (unsigned short)((unsigned)pa.__x | ((unsigned)pb.__x << 8));
}

// ---------------------------------------------------------------- CSR build (atomic-free)
// P1: 391 blocks x 512 threads, 4096 edges each. rec = (buk:9)<<23 | (rlow:7)<<16 | col:16.

__global__ __launch_bounds__(512) void partition_edges(const int* __restrict__ row,
                                                       const int* __restrict__ col,
                                                       int* __restrict__ bucket_cnt,
                                                       unsigned* __restrict__ edge_buf) {
    __shared__ unsigned recs[P1_EDGES];     // 16 KB
    __shared__ unsigned sorted[P1_EDGES];   // 16 KB
    __shared__ int hist4[4][NBUK];          // per-wave-pair counts -> local bases
    __shared__ int cur4[4][NBUK];
    __shared__ int gbase[NBUK];
    __shared__ int scan[512];
    int tid = threadIdx.x;
    int w2 = tid >> 7;                      // wave-pair 0..3
    int e0 = blockIdx.x * P1_EDGES;
    int m = N_EDGES - e0; if (m > P1_EDGES) m = P1_EDGES;

    for (int i = tid; i < 4 * NBUK; i += 512) ((int*)hist4)[i] = 0;
    for (int i = tid; i < 4 * NBUK; i += 512) ((int*)cur4)[i] = 0;
    __syncthreads();
    for (int i = tid; i < m; i += 512) {
        int r = row[e0 + i];
        int c = col[e0 + i];
        int buk = r >> 7;
        recs[i] = ((unsigned)buk << 23) | ((unsigned)(r & 127) << 16) | (unsigned)c;
        atomicAdd(&hist4[w2][buk], 1);
    }
    __syncthreads();
    int tot = 0;
    if (tid < NBUK) tot = hist4[0][tid] + hist4[1][tid] + hist4[2][tid] + hist4[3][tid];
    scan[tid] = (tid < NBUK) ? tot : 0;
    __syncthreads();
    for (int off = 1; off < 512; off <<= 1) {
        int v = (tid >= off) ? scan[tid - off] : 0;
        __syncthreads();
        scan[tid] += v;
        __syncthreads();
    }
    if (tid < NBUK) {
        int run = (tid == 0) ? 0 : scan[tid - 1];   // block-local excl base
        gbase[tid] = (tot > 0) ? atomicAdd(&bucket_cnt[tid], tot) : 0;  // reserve range
#pragma unroll
        for (int w = 0; w < 4; ++w) {               // per-sub-group local bases
            int c = hist4[w][tid];
            hist4[w][tid] = run;
            run += c;
        }
    }
    __syncthreads();
    for (int i = tid; i < m; i += 512) {            // rank + reorder (bucket-major)
        unsigned rec = recs[i];
        int buk = rec >> 23;
        int rank = atomicAdd(&cur4[w2][buk], 1);
        sorted[hist4[w2][buk] + rank] = rec;
    }
    __syncthreads();
    for (int p = tid; p < m; p += 512) {            // coalesced-run writes
        unsigned rec = sorted[p];
        int buk = rec >> 23;
        edge_buf[(size_t)buk * BUK_CAP + gbase[buk] + (p - hist4[0][buk])] = rec;
    }
}

// P2: one block per bucket (391 x 512); inline scan of bucket_cnt; LDS-cursor scatter.
__global__ __launch_bounds__(512) void finalize_csr(const unsigned* __restrict__ edge_buf,
                                                    const int* __restrict__ bucket_cnt,
                                                    int* __restrict__ rowptr,
                                                    float* __restrict__ invdeg,
                                                    unsigned short* __restrict__ csr_col) {
    __shared__ int hist[128], excl[128], cur[128];
    __shared__ int scan[512];
    int b = blockIdx.x;
    int tid = threadIdx.x;
    scan[tid] = (tid < NBUK) ? bucket_cnt[tid] : 0;
    __syncthreads();
    for (int off = 1; off < 512; off <<= 1) {
        int v = (tid >= off) ? scan[tid - off] : 0;
        __syncthreads();
        scan[tid] += v;
        __syncthreads();
    }
    int cnt = bucket_cnt[b];
    int base = (b == 0) ? 0 : scan[b - 1];
    const unsigned* src = edge_buf + (size_t)b * BUK_CAP;
    __syncthreads();
    if (tid < 128) { hist[tid] = 0; cur[tid] = 0; }
    __syncthreads();
    for (int i = tid; i < cnt; i += 512)
        atomicAdd(&hist[(src[i] >> 16) & 127], 1);
    __syncthreads();
    scan[tid] = (tid < 128) ? hist[tid] : 0;
    __syncthreads();
    for (int off = 1; off < 512; off <<= 1) {
        int v = (tid >= off) ? scan[tid - off] : 0;
        __syncthreads();
        scan[tid] += v;
        __syncthreads();
    }
    if (tid < 128) excl[tid] = (tid == 0) ? 0 : scan[tid - 1];
    __syncthreads();
    int r = b * 128 + tid;
    if (tid < 128 && r < N_NODES) {
        rowptr[r] = base + excl[tid];
        invdeg[r] = 1.0f / (float)(hist[tid] + 1);   // +1: self loop
    }
    if (b == NBUK - 1 && tid == 0) rowptr[N_NODES] = base + cnt;
    for (int i = tid; i < cnt; i += 512) {
        unsigned rec = src[i];
        int rl = (rec >> 16) & 127;
        int pos = excl[rl] + atomicAdd(&cur[rl], 1);
        csr_col[base + pos] = (unsigned short)(rec & 0xFFFFu);
    }
}

// ---------------------------------------------------------------- merged prep
// [0,12500): convert_x; [12500,12756): make_w1p; [12756,12790): fold_w + graph bounds.

__global__ __launch_bounds__(256) void prep(const float* __restrict__ x,
                                            unsigned short* __restrict__ xf,
                                            const float* __restrict__ w1,
                                            unsigned short* __restrict__ w1p,
                                            const float* __restrict__ w2,
                                            const float* __restrict__ wc,
                                            const float* __restrict__ b2,
                                            const float* __restrict__ bc,
                                            const int* __restrict__ batch,
                                            float* __restrict__ wcomb,
                                            float* __restrict__ bcomb,
                                            int* __restrict__ gcnt,
                                            int* __restrict__ gstart) {
    int b = blockIdx.x;
    int tid = threadIdx.x;
    if (b < 12500) {                                // convert_x: 12500*256 == N*64 exactly
        int i = b * 256 + tid;
        float2 v = ((const float2*)x)[i];
        xf[i] = fp8x2_enc(v.x, v.y);
        return;
    }
    if (b < 12756) {                                // make_w1p: 256 blocks, 65536 elems
        int i = (b - 12500) * 256 + tid;
        int j = i & 7, lane = (i >> 3) & 63, s = (i >> 9) & 3, t = i >> 11;
        int k = s * 32 + (lane >> 4) * 8 + j;
        int n = t * 16 + (lane & 15);
        w1p[i] = f2bf(w1[(size_t)k * D_H + n]);
        return;
    }
    int fb = b - 12756;                             // fold_w blocks 0..33
    if (fb == 33) {
        if (tid < N_GRAPHS) {
            int g = tid;
            int lo = 0, hi = N_NODES;
            while (lo < hi) { int mid = (lo + hi) >> 1; if (batch[mid] < g) lo = mid + 1; else hi = mid; }
            int a = lo;
            lo = 0; hi = N_NODES;
            while (lo < hi) { int mid = (lo + hi) >> 1; if (batch[mid] < g + 1) lo = mid + 1; else hi = mid; }
            gcnt[g] = lo - a;
            gstart[g] = a;
            if (g == N_GRAPHS - 1) gstart[N_GRAPHS] = N_NODES;
        }
        return;
    }
    int o = tid & 15, kl = tid >> 4;
    int k = fb * 16 + kl;
    if (k > D_H) return;
    const float* wr = (k < D_H) ? (w2 + (size_t)k * D_H) : b2;
    float s = 0.f;
    for (int j = 0; j < D_H; j += 4) {
        s += wr[j + 0] * wc[(j + 0) * D_OUT + o]
           + wr[j + 1] * wc[(j + 1) * D_OUT + o]
           + wr[j + 2] * wc[(j + 2) * D_OUT + o]
           + wr[j + 3] * wc[(j + 3) * D_OUT + o];
    }
    if (k < D_H) wcomb[k * D_OUT + o] = s;
    else         bcomb[o] = s + bc[o];
}

// ---------------------------------------------------------------- propagation (fp8 storage, f32 accumulate)
// Frozen shape (12 rounds of probes): one row per wave, full-wave contiguous 128B
// row gather, shfl-broadcast indices, 16 gathers in flight.

__global__ __launch_bounds__(128) void propagate_fp8(const unsigned short* __restrict__ xin,
                                                     unsigned short* __restrict__ out8,
                                                     unsigned* __restrict__ out16,
                                                     int last, float extra,
                                                     const int* __restrict__ rowptr,
                                                     const unsigned short* __restrict__ csr_col,
                                                     const float* __restrict__ invdeg) {
    int wave = threadIdx.x >> 6;
    int lane = threadIdx.x & 63;
    int r = blockIdx.x * 2 + wave;
    if (r >= N_NODES) return;
    int beg = rowptr[r], end = rowptr[r + 1];
    float2 sv = fp8x2_dec(xin[(size_t)r * 64 + lane]);   // self loop
    float acc0 = sv.x, acc1 = sv.y;
    for (int cs = beg; cs < end; cs += 64) {
        int nn = end - cs; if (nn > 64) nn = 64;
        int colv = (int)csr_col[cs + (lane < nn ? lane : 0)];
        int j = 0;
        for (; j + 16 <= nn; j += 16) {           // 16 independent 128B gathers in flight
            unsigned short uu[16];
#pragma unroll
            for (int q = 0; q < 16; ++q) {
                int c = __shfl(colv, j + q, 64);
                uu[q] = xin[(size_t)c * 64 + lane];
            }
#pragma unroll
            for (int q = 0; q < 16; ++q) {
                float2 v = fp8x2_dec(uu[q]);
                acc0 += v.x; acc1 += v.y;
            }
        }
        for (; j + 4 <= nn; j += 4) {
            unsigned short u0, u1, u2, u3;
            {
                int c0 = __shfl(colv, j + 0, 64), c1 = __shfl(colv, j + 1, 64);
                int c2 = __shfl(colv, j + 2, 64), c3 = __shfl(colv, j + 3, 64);
                u0 = xin[(size_t)c0 * 64 + lane];
                u1 = xin[(size_t)c1 * 64 + lane];
                u2 = xin[(size_t)c2 * 64 + lane];
                u3 = xin[(size_t)c3 * 64 + lane];
            }
            float2 v0 = fp8x2_dec(u0), v1 = fp8x2_dec(u1);
            float2 v2 = fp8x2_dec(u2), v3 = fp8x2_dec(u3);
            acc0 += v0.x + v1.x + v2.x + v3.x;
            acc1 += v0.y + v1.y + v2.y + v3.y;
        }
        for (; j < nn; ++j) {
            int c = __shfl(colv, j, 64);
            float2 v = fp8x2_dec(xin[(size_t)c * 64 + lane]);
            acc0 += v.x; acc1 += v.y;
        }
    }
    float s = invdeg[r] * extra;
    acc0 *= s; acc1 *= s;
    if (last) {
        out16[(size_t)r * 64 + lane] = (unsigned)f2bf(acc0) | ((unsigned)f2bf(acc1) << 16);
    } else {
        out8[(size_t)r * 64 + lane] = fp8x2_enc(acc0, acc1);
    }
}

// ---------------------------------------------------------------- MFMA GEMM + pool, register-only epilogue
// grid (64 graphs, 4 col-groups, MSPLIT) = 2048 blocks (8/CU). Pool sum computed
// straight from the MFMA C-layout: lane (col=l15, quad) holds rows quad*4+rg of the
// wave's 16-row strip -> per-lane reg sum + shfl_xor(16,32). No per-tile barriers,
// no 34KB LDS tile (only 2KB cross-wave buffer). Zero atomics.

__global__ __launch_bounds__(256) void gemm_graph_pool(const unsigned short* __restrict__ h3b,
                                                       const unsigned short* __restrict__ w1p,
                                                       const float* __restrict__ b1,
                                                       const int* __restrict__ gstart,
                                                       float* __restrict__ gsum) {
    __shared__ float wsum[4][128];
    int tid = threadIdx.x;
    int lane = tid & 63, wave = tid >> 6;
    int quad = lane >> 4, l15 = lane & 15;
    int g = blockIdx.x;
    int nbase = blockIdx.y * 128;
    int ms = blockIdx.z;
    int r0 = gstart[g], r1 = gstart[g + 1];

    float b1v[8];
#pragma unroll
    for (int t = 0; t < 8; ++t) b1v[t] = b1[nbase + t * 16 + l15];

    const unsigned short* bbase = w1p + ((size_t)(blockIdx.y * 8) * 4 * 64 + lane) * 8;

    float gaccT[8];
#pragma unroll
    for (int t = 0; t < 8; ++t) gaccT[t] = 0.f;

    for (int mbase = r0 + ms * 64; mbase < r1; mbase += 64 * MSPLIT) {
        int m = mbase + wave * 16 + l15;
        int mc = m < N_NODES ? m : N_NODES - 1;      // clamp; invalid rows masked below
        const unsigned short* arow = h3b + (size_t)mc * 128 + quad * 8;
        bf16x8 afrag[4];
#pragma unroll
        for (int s = 0; s < 4; ++s)
            afrag[s] = *(const bf16x8*)(arow + s * 32);

        int rowbase = mbase + wave * 16 + quad * 4;  // this lane's C rows: rowbase+rg
#pragma unroll
        for (int t = 0; t < 8; ++t) {
            f32x4 acc = (f32x4){0.f, 0.f, 0.f, 0.f};
#pragma unroll
            for (int s = 0; s < 4; ++s) {
                bf16x8 bfrag = *(const bf16x8*)(bbase + (size_t)(t * 4 + s) * 64 * 8);
                acc = __builtin_amdgcn_mfma_f32_16x16x32_bf16(afrag[s], bfrag, acc, 0, 0, 0);
            }
#pragma unroll
            for (int rg = 0; rg < 4; ++rg) {
                float v = acc[rg] + b1v[t];
                v = v > 0.f ? v : 0.f;
                gaccT[t] += (rowbase + rg < r1) ? v : 0.f;
            }
        }
    }
    // sum the 4 quads (rows 0..15 of the wave strip) per column
#pragma unroll
    for (int t = 0; t < 8; ++t) {
        gaccT[t] += __shfl_xor(gaccT[t], 16, 64);
        gaccT[t] += __shfl_xor(gaccT[t], 32, 64);
    }
    if (quad == 0) {
#pragma unroll
        for (int t = 0; t < 8; ++t)
            wsum[wave][t * 16 + l15] = gaccT[t];
    }
    __syncthreads();
    if (tid < 128)
        gsum[((size_t)ms * N_GRAPHS + g) * D_H + nbase + tid] =
            wsum[0][tid] + wsum[1][tid] + wsum[2][tid] + wsum[3][tid];
}

// ---------------------------------------------------------------- final: mean + folded (512x16) projection

__global__ __launch_bounds__(256) void final_pool(const float* __restrict__ gsum,
                                                  const int* __restrict__ gcnt,
                                                  const float* __restrict__ wcomb,
                                                  const float* __restrict__ bcomb,
                                                  float* __restrict__ out) {
    int g = blockIdx.x;
    int tid = threadIdx.x;
    __shared__ float p[D_H];
    __shared__ float part[16][17];
    int c = gcnt[g]; if (c < 1) c = 1;
    float inv = 1.0f / (float)c;
#pragma unroll
    for (int h = 0; h < 2; ++h) {
        int i = tid + h * 256;
        float v = 0.f;
#pragma unroll
        for (int ms = 0; ms < MSPLIT; ++ms)
            v += gsum[((size_t)ms * N_GRAPHS + g) * D_H + i];
        p[i] = v * inv;
    }
    __syncthreads();
    int o = tid & 15, ch = tid >> 4;
    int k0 = ch * 32;
    float s = 0.f;
    for (int k = k0; k < k0 + 32; ++k)
        s += p[k] * wcomb[k * D_OUT + o];
    part[ch][o] = s;
    __syncthreads();
    if (tid < D_OUT) {
        float t = bcomb[tid];
        for (int ch2 = 0; ch2 < 16; ++ch2) t += part[ch2][tid];
        out[g * D_OUT + tid] = t;
    }
}

// ---------------------------------------------------------------- launch

extern "C" void kernel_launch(void* const* d_in, const int* in_sizes, int n_in,
                              void* d_out, int out_size, void* d_ws, size_t ws_size,
                              hipStream_t stream) {
    const float* x     = (const float*)d_in[0];
    const int*   eidx  = (const int*)d_in[1];   // [2, E]
    const int*   batch = (const int*)d_in[2];
    const float* w1    = (const float*)d_in[3];
    const float* b1    = (const float*)d_in[4];
    const float* w2    = (const float*)d_in[5];
    const float* b2    = (const float*)d_in[6];
    const float* wc    = (const float*)d_in[7];
    const float* bc    = (const float*)d_in[8];
    float* out = (float*)d_out;
    const int* row = eidx;
    const int* col = eidx + N_EDGES;

    char* p = (char*)d_ws;
    auto alloc = [&](size_t bytes) { char* q = p; p += (bytes + 255) & ~(size_t)255; return q; };
    // zero-init region: only bucket_cnt
    char* zbase = p;
    int*   bucket_cnt = (int*)alloc((size_t)NBUK * 4);
    size_t zbytes = (size_t)(p - zbase);
    float* gsum    = (float*)alloc((size_t)MSPLIT * N_GRAPHS * D_H * 4);
    int*   rowptr  = (int*)alloc((size_t)(N_NODES + 1) * 4);
    int*   gcnt    = (int*)alloc((size_t)N_GRAPHS * 4);
    int*   gstart  = (int*)alloc((size_t)(N_GRAPHS + 1) * 4);
    float* invdeg  = (float*)alloc((size_t)N_NODES * 4);
    float* wcomb   = (float*)alloc((size_t)D_H * D_OUT * 4);
    float* bcomb   = (float*)alloc((size_t)D_OUT * 4);
    unsigned* edge_buf = (unsigned*)alloc((size_t)NBUK * BUK_CAP * 4);
    unsigned short* csr_col = (unsigned short*)alloc((size_t)N_EDGES * 2);
    unsigned short* xf  = (unsigned short*)alloc((size_t)N_NODES * 64 * 2);  // fp8x2
    unsigned short* h0f = (unsigned short*)alloc((size_t)N_NODES * 64 * 2);  // fp8x2
    unsigned short* h1f = (unsigned short*)alloc((size_t)N_NODES * 64 * 2);  // fp8x2
    unsigned* h3b  = (unsigned*)alloc((size_t)N_NODES * 64 * 4);             // bf16x2 node-major
    unsigned short* w1p = (unsigned short*)alloc((size_t)D_IN * D_H * 2);

    (void)hipMemsetAsync(zbase, 0, zbytes, stream);

    prep<<<12790, 256, 0, stream>>>(x, xf, w1, w1p, w2, wc, b2, bc, batch,
                                    wcomb, bcomb, gcnt, gstart);

    partition_edges<<<P1_BLOCKS, 512, 0, stream>>>(row, col, bucket_cnt, edge_buf);
    finalize_csr<<<NBUK, 512, 0, stream>>>(edge_buf, bucket_cnt, rowptr, invdeg, csr_col);

    int pgrid = (N_NODES + 1) / 2;
    propagate_fp8<<<pgrid, 128, 0, stream>>>(xf,  h0f, nullptr, 0, 8.0f,
                                             rowptr, csr_col, invdeg);
    propagate_fp8<<<pgrid, 128, 0, stream>>>(h0f, h1f, nullptr, 0, 8.0f,
                                             rowptr, csr_col, invdeg);
    propagate_fp8<<<pgrid, 128, 0, stream>>>(h1f, nullptr, h3b, 1, 1.0f / 64.0f,
                                             rowptr, csr_col, invdeg);

    dim3 ggrid(N_GRAPHS, D_H / 128, MSPLIT);
    gemm_graph_pool<<<ggrid, 256, 0, stream>>>((const unsigned short*)h3b, w1p, b1,
                                               gstart, gsum);
    final_pool<<<N_GRAPHS, 256, 0, stream>>>(gsum, gcnt, wcomb, bcomb, out);
}